// Round 18
// baseline (818.157 us; speedup 1.0000x reference)
//
#include <hip/hip_runtime.h>
#include <hip/hip_bf16.h>

typedef int int4v __attribute__((ext_vector_type(4)));
typedef long long i64;
typedef long long i64x2 __attribute__((ext_vector_type(2)));
typedef unsigned long long u64;
typedef unsigned int u32;

#define DT 0.01f

// sin(x) with Cody-Waite reduction mod pi, accurate to ~2e-7 for |x| < ~6000.
__device__ __forceinline__ float fast_sin(float x) {
  const float INVPI = 0.3183098861837907f;
  float n = rintf(x * INVPI);
  int ni = (int)n;
  float r = fmaf(n, -3.140625f, x);
  r = fmaf(n, -9.6765358979e-4f, r);
  float s = r * r;
  float p = fmaf(s, -2.5052108e-8f, 2.7557319e-6f);
  p = fmaf(s, p, -1.9841270e-4f);
  p = fmaf(s, p, 8.3333333e-3f);
  p = fmaf(s, p, -1.6666667e-1f);
  float res = fmaf(r * s, p, r);
  return (ni & 1) ? -res : res;
}

typedef float f32x16 __attribute__((ext_vector_type(16)));
// (kept for the fp32 fallback kernel)
__device__ __forceinline__ void sload4(const float* p, f32x16& a, f32x16& b,
                                       f32x16& c, f32x16& d) {
  asm volatile(
      "s_load_dwordx16 %0, %4, 0\n\t"
      "s_load_dwordx16 %1, %4, 0x40\n\t"
      "s_load_dwordx16 %2, %4, 0x80\n\t"
      "s_load_dwordx16 %3, %4, 0xc0\n\t"
      "s_waitcnt lgkmcnt(0)"
      : "=s"(a), "=s"(b), "=s"(c), "=s"(d)
      : "s"(p));
}

// K0 partial column sums (m split in 2 halves for occupancy).
__global__ __launch_bounds__(256) void kPrep1(const float* __restrict__ k0,
                                              float* __restrict__ K0p) {
  const int id = (blockIdx.x & 255) * 256 + threadIdx.x;
  const int p = blockIdx.x >> 8;
  const int h = id >> 9, j = id & 511;
  const float* q = k0 + (size_t)h * 262144 + (size_t)(p * 256) * 512 + j;
  float s = 0.f;
  for (int m = 0; m < 256; ++m) s += q[(size_t)m * 512];
  K0p[p * 65536 + id] = s;
}

// K1s[h,j] = sum_m k1[h,m,j]
__global__ __launch_bounds__(256) void kPrep2(const float* __restrict__ k1,
                                              float* __restrict__ K1s) {
  int t = blockIdx.x * 256 + threadIdx.x;
  int h = t >> 7, j = t & 127;
  const float* p = k1 + (size_t)h * 65536 + j;
  float s = 0.f;
  for (int m = 0; m < 512; ++m) s += p[(size_t)m * 128];
  K1s[t] = s;
}

// M[l,j] = sum_h K1s[l,h] * (K0pA[h,j] + K0pB[h,j])
__global__ __launch_bounds__(256) void kPrep3(const float* __restrict__ K0p,
                                              const float* __restrict__ K1s,
                                              float* __restrict__ M) {
  int t = blockIdx.x * 256 + threadIdx.x;
  int l = t >> 9, j = t & 511;
  float s = 0.f;
#pragma unroll 8
  for (int h = 0; h < 128; ++h)
    s = fmaf(K1s[l * 128 + h], K0p[h * 512 + j] + K0p[65536 + h * 512 + j], s);
  M[t] = s;
}

// Mnorm = max_l sum_j |M[l,j]|  (one block; 8 threads per l)
__global__ __launch_bounds__(1024) void kNorm(const float* __restrict__ M,
                                              float* __restrict__ Mnorm) {
  __shared__ float red[128];
  const int t = threadIdx.x;
  const int l = t >> 3, seg = t & 7;
  const float* row = M + l * 512 + seg * 64;
  float s = 0.f;
#pragma unroll 8
  for (int i = 0; i < 64; ++i) s += fabsf(row[i]);
#pragma unroll
  for (int off = 4; off > 0; off >>= 1) s += __shfl_down(s, off, 8);
  if (seg == 0) red[l] = s;
  __syncthreads();
  if (t == 0) {
    float m = 0.f;
    for (int i = 0; i < 128; ++i) m = fmaxf(m, red[i]);
    Mnorm[0] = m;
  }
}

// Per-row int16 quantization of k2 into interleaved i8 planes in MFMA
// fragment order (see R17). q cannot round past 32767 (32767*2eps << 0.5).
__global__ __launch_bounds__(256) void kConvRow(const float* __restrict__ k2,
                                                i64x2* __restrict__ kF2,
                                                float* __restrict__ rowinv,
                                                float* __restrict__ crow) {
  const int t = threadIdx.x;
  const int row = blockIdx.x * 16 + (t >> 4);
  const int seg = t & 15;
  const float* src = k2 + (size_t)row * 128 + seg * 8;
  const float4 a = *(const float4*)(src);
  const float4 b = *(const float4*)(src + 4);
  float m = fmaxf(fmaxf(fmaxf(fabsf(a.x), fabsf(a.y)), fmaxf(fabsf(a.z), fabsf(a.w))),
                  fmaxf(fmaxf(fabsf(b.x), fabsf(b.y)), fmaxf(fabsf(b.z), fabsf(b.w))));
#pragma unroll
  for (int off = 8; off > 0; off >>= 1) m = fmaxf(m, __shfl_xor(m, off, 64));
  const float scale = m > 0.f ? 32767.0f / m : 0.f;
  if (seg == 0) rowinv[row] = m > 0.f ? m / 32767.0f : 0.f;
  const float v[8] = {a.x, a.y, a.z, a.w, b.x, b.y, b.z, b.w};
  u64 ph = 0, pl = 0;
  int csum = 0;
#pragma unroll
  for (int i = 0; i < 8; ++i) {
    const int q = (int)rintf(v[i] * scale);
    const int kh = q >> 8;
    const int kl = (q & 255) - 128;
    ph |= (u64)(unsigned char)(signed char)kh << (8 * i);
    pl |= (u64)(unsigned char)(signed char)kl << (8 * i);
    csum += q - 128;
  }
  i64x2 wv;
  wv.x = (i64)ph;
  wv.y = (i64)pl;
  kF2[((size_t)(row >> 4) * 4 + (seg >> 2)) * 64 + (seg & 3) * 16 + (row & 15)] = wv;
#pragma unroll
  for (int off = 8; off > 0; off >>= 1) csum += __shfl_xor(csum, off, 64);
  if (seg == 0) crow[row] = 32896.f * (float)csum;
}

// Kernel A v3: RK4 bookkeeping + s2 GEMV + PRODUCER-SIDE s-quantization.
// Per-b scale from the conservative bound Mnorm*max|y_b| (>= true max|s2|,
// consistent across all lg blocks of the same b). Leaders quantize their 8
// s2 values into the 3 global i8 planes; cb partials go to disjoint
// cbPart[b][lg] (no atomics). kB then needs no quant phases at all.
__global__ __launch_bounds__(256) void kA2(
    const float* __restrict__ y0, const float* __restrict__ bias,
    const float* __restrict__ M, const float* __restrict__ aggp,
    float* __restrict__ ybuf, float* __restrict__ racc,
    float* __restrict__ s2T,        // kept for the fp32 fallback path
    float* __restrict__ out,
    const float* __restrict__ Mnorm,
    signed char* __restrict__ sqG,  // 3 planes x [16][128]
    float* __restrict__ sinvB,      // [16]
    float* __restrict__ cbPart,     // [16][16]
    int stage, int step) {
  __shared__ float ystage[512];
  __shared__ float ymW[4];
  __shared__ float red2[8];
  const int b = blockIdx.x >> 4, lg = blockIdx.x & 15, t = threadIdx.x;
  const float* ycur = ybuf + (step & 1) * 8192;
  float* ynext = ybuf + ((step + 1) & 1) * 8192;

  float ay = 0.f;
  for (int i = t; i < 512; i += 256) {
    const int idx = b * 512 + i;
    const bool own = (i >> 5) == lg;
    float ys;
    if (stage == 0) {
      ys = y0[idx];
      if (own) ynext[idx] = ys;
    } else {
      const float r = bias[idx] - (aggp[idx] + aggp[8192 + idx]);
      const float yb = ycur[idx];
      if (stage == 1) {
        ys = fmaf(0.5f * DT, r, yb);
        if (own) racc[idx] = r;
      } else if (stage == 2) {
        ys = fmaf(0.5f * DT, r, yb);
        if (own) racc[idx] = racc[idx] + 2.f * r;
      } else if (stage == 3) {
        ys = fmaf(DT, r, yb);
        if (own) racc[idx] = racc[idx] + 2.f * r;
      } else {
        ys = yb + (DT / 6.f) * (racc[idx] + r);
        if (own) { ynext[idx] = ys; out[step * 8192 + idx] = ys; }
      }
    }
    ystage[i] = ys;
    ay = fmaxf(ay, fabsf(ys));
  }
#pragma unroll
  for (int off = 32; off > 0; off >>= 1) ay = fmaxf(ay, __shfl_xor(ay, off, 64));
  if ((t & 63) == 0) ymW[t >> 6] = ay;
  __syncthreads();

  const float ymax = fmaxf(fmaxf(ymW[0], ymW[1]), fmaxf(ymW[2], ymW[3]));
  const float bound = Mnorm[0] * ymax;
  const float scaleB = bound > 0.f ? 8388607.f / bound : 0.f;
  const float sinv = bound > 0.f ? bound / 8388607.f : 0.f;

  const int g = t >> 5, u = t & 31;
  const int l = lg * 8 + g;
  const float* Mrow = M + l * 512;
  const int i0 = u * 16;
  float p = 0.f;
#pragma unroll
  for (int k = 0; k < 4; ++k) {
    const int off = ((u + k) & 3) << 2;
    const float4 mv = *(const float4*)(Mrow + i0 + off);
    const float4 yv = *(const float4*)(ystage + i0 + off);
    p = fmaf(mv.x, yv.x, p);
    p = fmaf(mv.y, yv.y, p);
    p = fmaf(mv.z, yv.z, p);
    p = fmaf(mv.w, yv.w, p);
  }
#pragma unroll
  for (int off = 16; off > 0; off >>= 1) p += __shfl_down(p, off, 32);
  if (u == 0) {
    s2T[l * 16 + b] = p;   // fallback-path consumer only
    int q = (int)rintf(p * scaleB);
    q = q > 8388607 ? 8388607 : (q < -8388607 ? -8388607 : q);
    const int sh = q >> 16;
    const int sm = ((q >> 8) & 255) - 128;
    const int sl = (q & 255) - 128;
    sqG[b * 128 + l] = (signed char)sh;
    sqG[2048 + b * 128 + l] = (signed char)sm;
    sqG[4096 + b * 128 + l] = (signed char)sl;
    red2[g] = 8388608.f * (float)sh + 32768.f * (float)sm + 128.f * (float)sl;
  }
  __syncthreads();
  if (t == 0) {
    float s = 0.f;
#pragma unroll
    for (int k = 0; k < 8; ++k) s += red2[k];
    cbPart[b * 16 + lg] = s;
    sinvB[b] = sinv;
  }
}

// Kernel B (i8 MFMA, fragment-order k planes, consumer-side quant REMOVED):
// starts directly with frag loads; B-frags come from the 6KB global planes
// (L2-broadcast across all 1024 blocks). Decomposition math identical to
// R16/R17 (exact integer GEMM); only the s-scale is now the conservative
// producer-side bound.
__global__ __launch_bounds__(256) void kBi8(
    const i64x2* __restrict__ kF2,
    const float* __restrict__ adj,
    const signed char* __restrict__ sqG,
    const float* __restrict__ sinvB, const float* __restrict__ cbPart,
    const float* __restrict__ rowinv, const float* __restrict__ crow,
    float* __restrict__ aggp) {
  __shared__ float cbL[16];
  __shared__ float part[64];
  const int t = threadIdx.x;
  const int lane = t & 63, w = t >> 6;
  const int bb = lane & 15, kg = lane >> 4;

  if (t < 16) {
    float s = 538968064.f;   // 128*32896*K (K=128)
#pragma unroll
    for (int g = 0; g < 16; ++g) s += cbPart[t * 16 + g];
    cbL[t] = s;
  }
  __syncthreads();

  i64 bA[4], bB[4], bC[4];
#pragma unroll
  for (int c = 0; c < 4; ++c) {
    const int kb = bb * 128 + c * 32 + kg * 8;
    bA[c] = *(const i64*)&sqG[kb];
    bB[c] = *(const i64*)&sqG[2048 + kb];
    bC[c] = *(const i64*)&sqG[4096 + kb];
  }
  const float sb = sinvB[bb], cbb = cbL[bb];

  const int rid0 = blockIdx.x * 256;
  const int l = rid0 >> 9;
  const int half = blockIdx.x & 1;

  float bacc = 0.f;
#pragma unroll
  for (int tt = 0; tt < 4; ++tt) {
    const int ridT = rid0 + w * 64 + tt * 16;
    const size_t tile = (size_t)(ridT >> 4);
    i64 ah[4], al[4];
#pragma unroll
    for (int c = 0; c < 4; ++c) {
      const i64x2 v = kF2[(tile * 4 + c) * 64 + lane];  // coalesced 16B/lane
      ah[c] = v.x;
      al[c] = v.y;
    }
    int4v Ga = {0, 0, 0, 0}, Gb = {0, 0, 0, 0}, Gc = {0, 0, 0, 0}, Gd = {0, 0, 0, 0};
#pragma unroll
    for (int c = 0; c < 4; ++c) {
      Ga = __builtin_amdgcn_mfma_i32_16x16x32_i8(ah[c], bA[c], Ga, 0, 0, 0);
      Gb = __builtin_amdgcn_mfma_i32_16x16x32_i8(ah[c], bB[c], Gb, 0, 0, 0);
      Gb = __builtin_amdgcn_mfma_i32_16x16x32_i8(al[c], bA[c], Gb, 0, 0, 0);
      Gc = __builtin_amdgcn_mfma_i32_16x16x32_i8(ah[c], bC[c], Gc, 0, 0, 0);
      Gc = __builtin_amdgcn_mfma_i32_16x16x32_i8(al[c], bB[c], Gc, 0, 0, 0);
      Gd = __builtin_amdgcn_mfma_i32_16x16x32_i8(al[c], bC[c], Gd, 0, 0, 0);
    }
    // epilogue: C/D row = kg*4 + reg, col = bb (verified layout)
    const int rbase = ridT + kg * 4;
    const float4 cr = *(const float4*)(crow + rbase);
    const float4 ri = *(const float4*)(rowinv + rbase);
    const float4 ad = *(const float4*)(adj + (size_t)bb * 262144 + rbase);
    const float crA[4] = {cr.x, cr.y, cr.z, cr.w};
    const float riA[4] = {ri.x, ri.y, ri.z, ri.w};
    const float adA[4] = {ad.x, ad.y, ad.z, ad.w};
    float ts = 0.f;
#pragma unroll
    for (int r = 0; r < 4; ++r) {
      const float dq = 16777216.f * (float)Ga[r] + 65536.f * (float)Gb[r] +
                       256.f * (float)Gc[r] + (float)Gd[r] + crA[r] + cbb;
      ts += adA[r] * fast_sin(dq * (riA[r] * sb));
    }
    ts += __shfl_xor(ts, 16, 64);
    ts += __shfl_xor(ts, 32, 64);
    bacc += ts;
  }
  if (lane < 16) part[w * 16 + lane] = bacc;
  __syncthreads();
  if (t < 16) {
    float ssum = part[t] + part[16 + t] + part[32 + t] + part[48 + t];
    aggp[half * 8192 + t * 512 + l] = ssum;   // aggp[half][b][l]
  }
}

// Kernel B fallback (fp32 k2, R4 body) — only if ws_size can't hold planes.
__global__ __launch_bounds__(256) void kBf32(
    const float* __restrict__ k2, const float* __restrict__ adj,
    const float* __restrict__ s2T, float* __restrict__ aggp) {
  __shared__ float lk[256 * 36];
  __shared__ float part[64];
  const int t = threadIdx.x;
  const int rid0 = blockIdx.x * 256;
  const int rid = rid0 + t;
  const int l = rid0 >> 9;
  const int half = blockIdx.x & 1;

  float dot[16];
#pragma unroll
  for (int b = 0; b < 16; ++b) dot[b] = 0.f;

  for (int c = 0; c < 4; ++c) {
    __syncthreads();
#pragma unroll
    for (int k = 0; k < 8; ++k) {
      const int f = k * 256 + t, row = f >> 3, e = f & 7;
      const float4 v = *(const float4*)(k2 + (size_t)(rid0 + row) * 128 + c * 32 + e * 4);
      *(float4*)(lk + row * 36 + e * 4) = v;
    }
    __syncthreads();
    const float* myrow = lk + t * 36;
#pragma unroll
    for (int q = 0; q < 8; ++q) {
      const float4 kv = *(const float4*)(myrow + q * 4);
      f32x16 sa, sb, sc, sd;
      sload4(s2T + (c * 32 + q * 4) * 16, sa, sb, sc, sd);
#pragma unroll
      for (int b = 0; b < 16; ++b) dot[b] = fmaf(sa[b], kv.x, dot[b]);
#pragma unroll
      for (int b = 0; b < 16; ++b) dot[b] = fmaf(sb[b], kv.y, dot[b]);
#pragma unroll
      for (int b = 0; b < 16; ++b) dot[b] = fmaf(sc[b], kv.z, dot[b]);
#pragma unroll
      for (int b = 0; b < 16; ++b) dot[b] = fmaf(sd[b], kv.w, dot[b]);
    }
  }

#pragma unroll
  for (int b = 0; b < 16; ++b) {
    float v = adj[(size_t)b * 262144 + rid] * fast_sin(dot[b]);
#pragma unroll
    for (int off = 32; off > 0; off >>= 1) v += __shfl_down(v, off, 64);
    if ((t & 63) == 0) part[(t >> 6) * 16 + b] = v;
  }
  __syncthreads();
  if (t < 16) {
    float ssum = part[t] + part[16 + t] + part[32 + t] + part[48 + t];
    aggp[half * 8192 + t * 512 + l] = ssum;
  }
}

extern "C" void kernel_launch(void* const* d_in, const int* in_sizes, int n_in,
                              void* d_out, int out_size, void* d_ws, size_t ws_size,
                              hipStream_t stream) {
  const float* y0   = (const float*)d_in[0];  // [16,512]
  const float* bias = (const float*)d_in[1];  // [16,512,1]
  const float* adj  = (const float*)d_in[2];  // [16,512,512]
  const float* k0   = (const float*)d_in[3];  // [128,512,512]
  const float* k1   = (const float*)d_in[4];  // [128,512,128]
  const float* k2   = (const float*)d_in[5];  // [512,512,128]
  float* out = (float*)d_out;                 // [8,16,512] f32

  float* w      = (float*)d_ws;
  float* K0p    = w;                 // 131072 floats
  float* K1s    = w + 131072;        // 16384
  float* M      = w + 147456;        // 65536
  float* Mnorm  = w + 212992;        // 16 (1 used)
  float* sinvB  = w + 213008;        // 16
  float* cbPart = w + 213024;        // 256
  float* s2T    = w + 213280;        // 2048  (fp32 fallback only)
  float* ybuf   = w + 215328;        // 16384
  float* racc   = w + 231712;        // 8192
  float* aggp   = w + 239904;        // 16384
  signed char* sqG = (signed char*)(w + 256288);  // 3 x 2048 B = 1536 floats
  float* rowinv = w + 257824;        // 262144
  float* crow   = w + 519968;        // 262144
  i64x2* kF2    = (i64x2*)(w + 782112);  // 64 MB interleaved i8 planes
  const bool useI8 =
      ws_size >= (size_t)782112 * 4 + (size_t)67108864;

  kPrep1<<<512, 256, 0, stream>>>(k0, K0p);
  kPrep2<<<64, 256, 0, stream>>>(k1, K1s);
  kPrep3<<<256, 256, 0, stream>>>(K0p, K1s, M);
  kNorm<<<1, 1024, 0, stream>>>(M, Mnorm);
  if (useI8) kConvRow<<<16384, 256, 0, stream>>>(k2, kF2, rowinv, crow);

  kA2<<<256, 256, 0, stream>>>(y0, bias, M, aggp, ybuf, racc, s2T, out,
                               Mnorm, sqG, sinvB, cbPart, 0, -1);

  for (int step = 0; step < 8; ++step) {
    for (int stage = 1; stage <= 4; ++stage) {
      if (useI8)
        kBi8<<<1024, 256, 0, stream>>>(kF2, adj, sqG, sinvB, cbPart,
                                       rowinv, crow, aggp);
      else
        kBf32<<<1024, 256, 0, stream>>>(k2, adj, s2T, aggp);
      kA2<<<256, 256, 0, stream>>>(y0, bias, M, aggp, ybuf, racc, s2T, out,
                                   Mnorm, sqG, sinvB, cbPart, stage, step);
    }
  }
}

// Round 19
// 739.224 us; speedup vs baseline: 1.1068x; 1.1068x over previous
//
#include <hip/hip_runtime.h>
#include <hip/hip_bf16.h>

typedef int int4v __attribute__((ext_vector_type(4)));
typedef long long i64;
typedef long long i64x2 __attribute__((ext_vector_type(2)));
typedef unsigned long long u64;
typedef unsigned int u32;

#define DT 0.01f

// sin(x) with Cody-Waite reduction mod pi, accurate to ~2e-7 for |x| < ~6000.
__device__ __forceinline__ float fast_sin(float x) {
  const float INVPI = 0.3183098861837907f;
  float n = rintf(x * INVPI);
  int ni = (int)n;
  float r = fmaf(n, -3.140625f, x);
  r = fmaf(n, -9.6765358979e-4f, r);
  float s = r * r;
  float p = fmaf(s, -2.5052108e-8f, 2.7557319e-6f);
  p = fmaf(s, p, -1.9841270e-4f);
  p = fmaf(s, p, 8.3333333e-3f);
  p = fmaf(s, p, -1.6666667e-1f);
  float res = fmaf(r * s, p, r);
  return (ni & 1) ? -res : res;
}

typedef float f32x16 __attribute__((ext_vector_type(16)));
// (kept for the fp32 fallback kernel)
__device__ __forceinline__ void sload4(const float* p, f32x16& a, f32x16& b,
                                       f32x16& c, f32x16& d) {
  asm volatile(
      "s_load_dwordx16 %0, %4, 0\n\t"
      "s_load_dwordx16 %1, %4, 0x40\n\t"
      "s_load_dwordx16 %2, %4, 0x80\n\t"
      "s_load_dwordx16 %3, %4, 0xc0\n\t"
      "s_waitcnt lgkmcnt(0)"
      : "=s"(a), "=s"(b), "=s"(c), "=s"(d)
      : "s"(p));
}

// K0 partial column sums (m split in 2 halves for occupancy).
__global__ __launch_bounds__(256) void kPrep1(const float* __restrict__ k0,
                                              float* __restrict__ K0p) {
  const int id = (blockIdx.x & 255) * 256 + threadIdx.x;
  const int p = blockIdx.x >> 8;
  const int h = id >> 9, j = id & 511;
  const float* q = k0 + (size_t)h * 262144 + (size_t)(p * 256) * 512 + j;
  float s = 0.f;
  for (int m = 0; m < 256; ++m) s += q[(size_t)m * 512];
  K0p[p * 65536 + id] = s;
}

// K1s[h,j] = sum_m k1[h,m,j]
__global__ __launch_bounds__(256) void kPrep2(const float* __restrict__ k1,
                                              float* __restrict__ K1s) {
  int t = blockIdx.x * 256 + threadIdx.x;
  int h = t >> 7, j = t & 127;
  const float* p = k1 + (size_t)h * 65536 + j;
  float s = 0.f;
  for (int m = 0; m < 512; ++m) s += p[(size_t)m * 128];
  K1s[t] = s;
}

// M[l,j] = sum_h K1s[l,h] * (K0pA[h,j] + K0pB[h,j])
__global__ __launch_bounds__(256) void kPrep3(const float* __restrict__ K0p,
                                              const float* __restrict__ K1s,
                                              float* __restrict__ M) {
  int t = blockIdx.x * 256 + threadIdx.x;
  int l = t >> 9, j = t & 511;
  float s = 0.f;
#pragma unroll 8
  for (int h = 0; h < 128; ++h)
    s = fmaf(K1s[l * 128 + h], K0p[h * 512 + j] + K0p[65536 + h * 512 + j], s);
  M[t] = s;
}

// Per-row int16 quantization of k2 into interleaved i8 planes in MFMA
// fragment order (see R17). q cannot round past 32767 (32767*2eps << 0.5).
__global__ __launch_bounds__(256) void kConvRow(const float* __restrict__ k2,
                                                i64x2* __restrict__ kF2,
                                                float* __restrict__ rowinv,
                                                float* __restrict__ crow) {
  const int t = threadIdx.x;
  const int row = blockIdx.x * 16 + (t >> 4);
  const int seg = t & 15;
  const float* src = k2 + (size_t)row * 128 + seg * 8;
  const float4 a = *(const float4*)(src);
  const float4 b = *(const float4*)(src + 4);
  float m = fmaxf(fmaxf(fmaxf(fabsf(a.x), fabsf(a.y)), fmaxf(fabsf(a.z), fabsf(a.w))),
                  fmaxf(fmaxf(fabsf(b.x), fabsf(b.y)), fmaxf(fabsf(b.z), fabsf(b.w))));
#pragma unroll
  for (int off = 8; off > 0; off >>= 1) m = fmaxf(m, __shfl_xor(m, off, 64));
  const float scale = m > 0.f ? 32767.0f / m : 0.f;
  if (seg == 0) rowinv[row] = m > 0.f ? m / 32767.0f : 0.f;
  const float v[8] = {a.x, a.y, a.z, a.w, b.x, b.y, b.z, b.w};
  u64 ph = 0, pl = 0;
  int csum = 0;
#pragma unroll
  for (int i = 0; i < 8; ++i) {
    const int q = (int)rintf(v[i] * scale);
    const int kh = q >> 8;
    const int kl = (q & 255) - 128;
    ph |= (u64)(unsigned char)(signed char)kh << (8 * i);
    pl |= (u64)(unsigned char)(signed char)kl << (8 * i);
    csum += q - 128;
  }
  i64x2 wv;
  wv.x = (i64)ph;
  wv.y = (i64)pl;
  kF2[((size_t)(row >> 4) * 4 + (seg >> 2)) * 64 + (seg & 3) * 16 + (row & 15)] = wv;
#pragma unroll
  for (int off = 8; off > 0; off >>= 1) csum += __shfl_xor(csum, off, 64);
  if (seg == 0) crow[row] = 32896.f * (float)csum;
}

// Kernel A v2 (R17 form): RK4 bookkeeping + s2T = transpose(M * y_stage).
// rhs now sums FOUR aggp quarters (kB grid split to 2048 blocks).
__global__ __launch_bounds__(256) void kA2(
    const float* __restrict__ y0, const float* __restrict__ bias,
    const float* __restrict__ M, const float* __restrict__ aggp,
    float* __restrict__ ybuf, float* __restrict__ racc,
    float* __restrict__ s2T, float* __restrict__ out,
    int stage, int step) {
  __shared__ float ystage[512];
  const int b = blockIdx.x >> 4, lg = blockIdx.x & 15, t = threadIdx.x;
  const float* ycur = ybuf + (step & 1) * 8192;
  float* ynext = ybuf + ((step + 1) & 1) * 8192;

  for (int i = t; i < 512; i += 256) {
    const int idx = b * 512 + i;
    const bool own = (i >> 5) == lg;
    float ys;
    if (stage == 0) {
      ys = y0[idx];
      if (own) ynext[idx] = ys;
    } else {
      const float r = bias[idx] - (aggp[idx] + aggp[8192 + idx] +
                                   aggp[16384 + idx] + aggp[24576 + idx]);
      const float yb = ycur[idx];
      if (stage == 1) {
        ys = fmaf(0.5f * DT, r, yb);
        if (own) racc[idx] = r;
      } else if (stage == 2) {
        ys = fmaf(0.5f * DT, r, yb);
        if (own) racc[idx] = racc[idx] + 2.f * r;
      } else if (stage == 3) {
        ys = fmaf(DT, r, yb);
        if (own) racc[idx] = racc[idx] + 2.f * r;
      } else {
        ys = yb + (DT / 6.f) * (racc[idx] + r);
        if (own) { ynext[idx] = ys; out[step * 8192 + idx] = ys; }
      }
    }
    ystage[i] = ys;
  }
  __syncthreads();

  const int g = t >> 5, u = t & 31;
  const int l = lg * 8 + g;
  const float* Mrow = M + l * 512;
  const int i0 = u * 16;
  float p = 0.f;
#pragma unroll
  for (int k = 0; k < 4; ++k) {
    const int off = ((u + k) & 3) << 2;
    const float4 mv = *(const float4*)(Mrow + i0 + off);
    const float4 yv = *(const float4*)(ystage + i0 + off);
    p = fmaf(mv.x, yv.x, p);
    p = fmaf(mv.y, yv.y, p);
    p = fmaf(mv.z, yv.z, p);
    p = fmaf(mv.w, yv.w, p);
  }
#pragma unroll
  for (int off = 16; off > 0; off >>= 1) p += __shfl_down(p, off, 32);
  if (u == 0) s2T[l * 16 + b] = p;
}

// Kernel B (i8 MFMA, R17 in-kernel-quant form, GRID SPLIT 1024->2048):
// each block covers 128 rows (2 tiles/wave) so more blocks are resident
// per CU -> more scheduler-visible independent work to hide load latency.
// Math byte-identical to R17 (absmax 0.05273438).
__global__ __launch_bounds__(256) void kBi8(
    const i64x2* __restrict__ kF2,
    const float* __restrict__ adj, const float* __restrict__ s2T,
    const float* __restrict__ rowinv, const float* __restrict__ crow,
    float* __restrict__ aggp) {
  __shared__ __align__(8) signed char sqA[16][136];  // sh plane, [b][k]
  __shared__ __align__(8) signed char sqB[16][136];  // sm
  __shared__ __align__(8) signed char sqC[16][136];  // sl
  __shared__ float sred[16][16];
  __shared__ float scaleL[16], sinvLs[16], cbLs[16];
  __shared__ float part[64];
  const int t = threadIdx.x;
  const int b16 = t & 15, jg = t >> 4;

  // phase 1: per-b absmax of s2T[j][b]
  float mx = 0.f;
#pragma unroll
  for (int i = 0; i < 8; ++i)
    mx = fmaxf(mx, fabsf(s2T[(jg * 8 + i) * 16 + b16]));
  sred[jg][b16] = mx;
  __syncthreads();
  if (t < 16) {
    float m = 0.f;
#pragma unroll
    for (int g = 0; g < 16; ++g) m = fmaxf(m, sred[g][t]);
    scaleL[t] = m > 0.f ? 8388607.f / m : 0.f;
    sinvLs[t] = m > 0.f ? m / 8388607.f : 0.f;
  }
  __syncthreads();
  // phase 2: quantize s to 3 i8 planes (transposed [b][k]) + cb partials
  {
    const float sc = scaleL[b16];
    u64 pa = 0, pb = 0, pc = 0;
    int ps2 = 0, psm = 0, psl = 0;
#pragma unroll
    for (int i = 0; i < 8; ++i) {
      int q = (int)rintf(s2T[(jg * 8 + i) * 16 + b16] * sc);
      q = q > 8388607 ? 8388607 : (q < -8388607 ? -8388607 : q);  // i8 wrap guard
      const int h = q >> 16;
      const int m = ((q >> 8) & 255) - 128;
      const int lo = (q & 255) - 128;
      pa |= (u64)(unsigned char)(signed char)h << (8 * i);
      pb |= (u64)(unsigned char)(signed char)m << (8 * i);
      pc |= (u64)(unsigned char)(signed char)lo << (8 * i);
      ps2 += h; psm += m; psl += lo;
    }
    *(u64*)&sqA[b16][jg * 8] = pa;
    *(u64*)&sqB[b16][jg * 8] = pb;
    *(u64*)&sqC[b16][jg * 8] = pc;
    sred[jg][b16] = 8388608.f * (float)ps2 + 32768.f * (float)psm + 128.f * (float)psl;
  }
  __syncthreads();
  if (t < 16) {
    float s = 0.f;
#pragma unroll
    for (int g = 0; g < 16; ++g) s += sred[g][t];
    cbLs[t] = s + 538968064.f;   // + 128*32896*K (K=128)
  }
  __syncthreads();

  // B fragments: lane (b=lane&15, kg=lane>>4) holds 8 k-bytes per chunk.
  const int lane = t & 63, w = t >> 6;
  const int bb = lane & 15, kg = lane >> 4;
  i64 bA[4], bB[4], bC[4];
#pragma unroll
  for (int c = 0; c < 4; ++c) {
    const int kb = c * 32 + kg * 8;
    bA[c] = *(const i64*)&sqA[bb][kb];
    bB[c] = *(const i64*)&sqB[bb][kb];
    bC[c] = *(const i64*)&sqC[bb][kb];
  }
  const float sb = sinvLs[bb], cbb = cbLs[bb];

  const int rid0 = blockIdx.x * 128;      // 128 rows per block now
  const int l = blockIdx.x >> 2;          // 4 blocks per l
  const int quarter = blockIdx.x & 3;

  float bacc = 0.f;
#pragma unroll
  for (int tt = 0; tt < 2; ++tt) {        // 2 tiles per wave
    const int ridT = rid0 + w * 32 + tt * 16;
    const size_t tile = (size_t)(ridT >> 4);
    i64 ah[4], al[4];
#pragma unroll
    for (int c = 0; c < 4; ++c) {
      const i64x2 v = kF2[(tile * 4 + c) * 64 + lane];  // coalesced 16B/lane
      ah[c] = v.x;
      al[c] = v.y;
    }
    int4v Ga = {0, 0, 0, 0}, Gb = {0, 0, 0, 0}, Gc = {0, 0, 0, 0}, Gd = {0, 0, 0, 0};
#pragma unroll
    for (int c = 0; c < 4; ++c) {
      Ga = __builtin_amdgcn_mfma_i32_16x16x32_i8(ah[c], bA[c], Ga, 0, 0, 0);
      Gb = __builtin_amdgcn_mfma_i32_16x16x32_i8(ah[c], bB[c], Gb, 0, 0, 0);
      Gb = __builtin_amdgcn_mfma_i32_16x16x32_i8(al[c], bA[c], Gb, 0, 0, 0);
      Gc = __builtin_amdgcn_mfma_i32_16x16x32_i8(ah[c], bC[c], Gc, 0, 0, 0);
      Gc = __builtin_amdgcn_mfma_i32_16x16x32_i8(al[c], bB[c], Gc, 0, 0, 0);
      Gd = __builtin_amdgcn_mfma_i32_16x16x32_i8(al[c], bC[c], Gd, 0, 0, 0);
    }
    // epilogue: C/D row = kg*4 + reg, col = bb (verified layout)
    const int rbase = ridT + kg * 4;
    const float4 cr = *(const float4*)(crow + rbase);
    const float4 ri = *(const float4*)(rowinv + rbase);
    const float4 ad = *(const float4*)(adj + (size_t)bb * 262144 + rbase);
    const float crA[4] = {cr.x, cr.y, cr.z, cr.w};
    const float riA[4] = {ri.x, ri.y, ri.z, ri.w};
    const float adA[4] = {ad.x, ad.y, ad.z, ad.w};
    float ts = 0.f;
#pragma unroll
    for (int r = 0; r < 4; ++r) {
      const float dq = 16777216.f * (float)Ga[r] + 65536.f * (float)Gb[r] +
                       256.f * (float)Gc[r] + (float)Gd[r] + crA[r] + cbb;
      ts += adA[r] * fast_sin(dq * (riA[r] * sb));
    }
    ts += __shfl_xor(ts, 16, 64);
    ts += __shfl_xor(ts, 32, 64);
    bacc += ts;
  }
  if (lane < 16) part[w * 16 + lane] = bacc;
  __syncthreads();
  if (t < 16) {
    float ssum = part[t] + part[16 + t] + part[32 + t] + part[48 + t];
    aggp[quarter * 8192 + t * 512 + l] = ssum;   // aggp[quarter][b][l]
  }
}

// Zero quarters 2-3 of aggp (fp32 fallback path writes only halves 0-1).
__global__ __launch_bounds__(256) void kZeroTail(float* __restrict__ aggp) {
  aggp[16384 + blockIdx.x * 256 + threadIdx.x] = 0.f;
}

// Kernel B fallback (fp32 k2, R4 body) — only if ws_size can't hold planes.
__global__ __launch_bounds__(256) void kBf32(
    const float* __restrict__ k2, const float* __restrict__ adj,
    const float* __restrict__ s2T, float* __restrict__ aggp) {
  __shared__ float lk[256 * 36];
  __shared__ float part[64];
  const int t = threadIdx.x;
  const int rid0 = blockIdx.x * 256;
  const int rid = rid0 + t;
  const int l = rid0 >> 9;
  const int half = blockIdx.x & 1;

  float dot[16];
#pragma unroll
  for (int b = 0; b < 16; ++b) dot[b] = 0.f;

  for (int c = 0; c < 4; ++c) {
    __syncthreads();
#pragma unroll
    for (int k = 0; k < 8; ++k) {
      const int f = k * 256 + t, row = f >> 3, e = f & 7;
      const float4 v = *(const float4*)(k2 + (size_t)(rid0 + row) * 128 + c * 32 + e * 4);
      *(float4*)(lk + row * 36 + e * 4) = v;
    }
    __syncthreads();
    const float* myrow = lk + t * 36;
#pragma unroll
    for (int q = 0; q < 8; ++q) {
      const float4 kv = *(const float4*)(myrow + q * 4);
      f32x16 sa, sb, sc, sd;
      sload4(s2T + (c * 32 + q * 4) * 16, sa, sb, sc, sd);
#pragma unroll
      for (int b = 0; b < 16; ++b) dot[b] = fmaf(sa[b], kv.x, dot[b]);
#pragma unroll
      for (int b = 0; b < 16; ++b) dot[b] = fmaf(sb[b], kv.y, dot[b]);
#pragma unroll
      for (int b = 0; b < 16; ++b) dot[b] = fmaf(sc[b], kv.z, dot[b]);
#pragma unroll
      for (int b = 0; b < 16; ++b) dot[b] = fmaf(sd[b], kv.w, dot[b]);
    }
  }

#pragma unroll
  for (int b = 0; b < 16; ++b) {
    float v = adj[(size_t)b * 262144 + rid] * fast_sin(dot[b]);
#pragma unroll
    for (int off = 32; off > 0; off >>= 1) v += __shfl_down(v, off, 64);
    if ((t & 63) == 0) part[(t >> 6) * 16 + b] = v;
  }
  __syncthreads();
  if (t < 16) {
    float ssum = part[t] + part[16 + t] + part[32 + t] + part[48 + t];
    aggp[half * 8192 + t * 512 + l] = ssum;
  }
}

extern "C" void kernel_launch(void* const* d_in, const int* in_sizes, int n_in,
                              void* d_out, int out_size, void* d_ws, size_t ws_size,
                              hipStream_t stream) {
  const float* y0   = (const float*)d_in[0];  // [16,512]
  const float* bias = (const float*)d_in[1];  // [16,512,1]
  const float* adj  = (const float*)d_in[2];  // [16,512,512]
  const float* k0   = (const float*)d_in[3];  // [128,512,512]
  const float* k1   = (const float*)d_in[4];  // [128,512,128]
  const float* k2   = (const float*)d_in[5];  // [512,512,128]
  float* out = (float*)d_out;                 // [8,16,512] f32

  float* w      = (float*)d_ws;
  float* K0p    = w;                 // 131072 floats
  float* K1s    = w + 131072;        // 16384
  float* M      = w + 147456;        // 65536
  float* s2T    = w + 212992;        // 2048
  float* ybuf   = w + 215040;        // 16384
  float* racc   = w + 231424;        // 8192
  float* aggp   = w + 239616;        // 32768 (4 quarters x [16][512])
  float* rowinv = w + 272384;        // 262144
  float* crow   = w + 534528;        // 262144
  i64x2* kF2    = (i64x2*)(w + 796672);  // 64 MB interleaved i8 planes
  const bool useI8 =
      ws_size >= (size_t)796672 * 4 + (size_t)67108864;

  kPrep1<<<512, 256, 0, stream>>>(k0, K0p);
  kPrep2<<<64, 256, 0, stream>>>(k1, K1s);
  kPrep3<<<256, 256, 0, stream>>>(K0p, K1s, M);
  if (useI8) kConvRow<<<16384, 256, 0, stream>>>(k2, kF2, rowinv, crow);
  else kZeroTail<<<64, 256, 0, stream>>>(aggp);   // fallback writes halves only

  kA2<<<256, 256, 0, stream>>>(y0, bias, M, aggp, ybuf, racc, s2T, out, 0, -1);

  for (int step = 0; step < 8; ++step) {
    for (int stage = 1; stage <= 4; ++stage) {
      if (useI8)
        kBi8<<<2048, 256, 0, stream>>>(kF2, adj, s2T, rowinv, crow, aggp);
      else
        kBf32<<<1024, 256, 0, stream>>>(k2, adj, s2T, aggp);
      kA2<<<256, 256, 0, stream>>>(y0, bias, M, aggp, ybuf, racc, s2T, out, stage, step);
    }
  }
}

// Round 20
// 720.786 us; speedup vs baseline: 1.1351x; 1.0256x over previous
//
#include <hip/hip_runtime.h>
#include <hip/hip_bf16.h>

typedef int int4v __attribute__((ext_vector_type(4)));
typedef long long i64;
typedef long long i64x2 __attribute__((ext_vector_type(2)));
typedef unsigned long long u64;
typedef unsigned int u32;

#define DT 0.01f

// sin(x) with Cody-Waite reduction mod pi, accurate to ~2e-7 for |x| < ~6000.
__device__ __forceinline__ float fast_sin(float x) {
  const float INVPI = 0.3183098861837907f;
  float n = rintf(x * INVPI);
  int ni = (int)n;
  float r = fmaf(n, -3.140625f, x);
  r = fmaf(n, -9.6765358979e-4f, r);
  float s = r * r;
  float p = fmaf(s, -2.5052108e-8f, 2.7557319e-6f);
  p = fmaf(s, p, -1.9841270e-4f);
  p = fmaf(s, p, 8.3333333e-3f);
  p = fmaf(s, p, -1.6666667e-1f);
  float res = fmaf(r * s, p, r);
  return (ni & 1) ? -res : res;
}

typedef float f32x16 __attribute__((ext_vector_type(16)));
// (kept for the fp32 fallback kernel)
__device__ __forceinline__ void sload4(const float* p, f32x16& a, f32x16& b,
                                       f32x16& c, f32x16& d) {
  asm volatile(
      "s_load_dwordx16 %0, %4, 0\n\t"
      "s_load_dwordx16 %1, %4, 0x40\n\t"
      "s_load_dwordx16 %2, %4, 0x80\n\t"
      "s_load_dwordx16 %3, %4, 0xc0\n\t"
      "s_waitcnt lgkmcnt(0)"
      : "=s"(a), "=s"(b), "=s"(c), "=s"(d)
      : "s"(p));
}

// K0 partial column sums (m split in 2 halves for occupancy).
__global__ __launch_bounds__(256) void kPrep1(const float* __restrict__ k0,
                                              float* __restrict__ K0p) {
  const int id = (blockIdx.x & 255) * 256 + threadIdx.x;
  const int p = blockIdx.x >> 8;
  const int h = id >> 9, j = id & 511;
  const float* q = k0 + (size_t)h * 262144 + (size_t)(p * 256) * 512 + j;
  float s = 0.f;
  for (int m = 0; m < 256; ++m) s += q[(size_t)m * 512];
  K0p[p * 65536 + id] = s;
}

// K1s[h,j] = sum_m k1[h,m,j]
__global__ __launch_bounds__(256) void kPrep2(const float* __restrict__ k1,
                                              float* __restrict__ K1s) {
  int t = blockIdx.x * 256 + threadIdx.x;
  int h = t >> 7, j = t & 127;
  const float* p = k1 + (size_t)h * 65536 + j;
  float s = 0.f;
  for (int m = 0; m < 512; ++m) s += p[(size_t)m * 128];
  K1s[t] = s;
}

// M[l,j] = sum_h K1s[l,h] * (K0pA[h,j] + K0pB[h,j])
__global__ __launch_bounds__(256) void kPrep3(const float* __restrict__ K0p,
                                              const float* __restrict__ K1s,
                                              float* __restrict__ M) {
  int t = blockIdx.x * 256 + threadIdx.x;
  int l = t >> 9, j = t & 511;
  float s = 0.f;
#pragma unroll 8
  for (int h = 0; h < 128; ++h)
    s = fmaf(K1s[l * 128 + h], K0p[h * 512 + j] + K0p[65536 + h * 512 + j], s);
  M[t] = s;
}

// Per-row int16 quantization of k2 into interleaved i8 planes in MFMA
// fragment order (see R17). q cannot round past 32767 (32767*2eps << 0.5).
__global__ __launch_bounds__(256) void kConvRow(const float* __restrict__ k2,
                                                i64x2* __restrict__ kF2,
                                                float* __restrict__ rowinv,
                                                float* __restrict__ crow) {
  const int t = threadIdx.x;
  const int row = blockIdx.x * 16 + (t >> 4);
  const int seg = t & 15;
  const float* src = k2 + (size_t)row * 128 + seg * 8;
  const float4 a = *(const float4*)(src);
  const float4 b = *(const float4*)(src + 4);
  float m = fmaxf(fmaxf(fmaxf(fabsf(a.x), fabsf(a.y)), fmaxf(fabsf(a.z), fabsf(a.w))),
                  fmaxf(fmaxf(fabsf(b.x), fabsf(b.y)), fmaxf(fabsf(b.z), fabsf(b.w))));
#pragma unroll
  for (int off = 8; off > 0; off >>= 1) m = fmaxf(m, __shfl_xor(m, off, 64));
  const float scale = m > 0.f ? 32767.0f / m : 0.f;
  if (seg == 0) rowinv[row] = m > 0.f ? m / 32767.0f : 0.f;
  const float v[8] = {a.x, a.y, a.z, a.w, b.x, b.y, b.z, b.w};
  u64 ph = 0, pl = 0;
  int csum = 0;
#pragma unroll
  for (int i = 0; i < 8; ++i) {
    const int q = (int)rintf(v[i] * scale);
    const int kh = q >> 8;
    const int kl = (q & 255) - 128;
    ph |= (u64)(unsigned char)(signed char)kh << (8 * i);
    pl |= (u64)(unsigned char)(signed char)kl << (8 * i);
    csum += q - 128;
  }
  i64x2 wv;
  wv.x = (i64)ph;
  wv.y = (i64)pl;
  kF2[((size_t)(row >> 4) * 4 + (seg >> 2)) * 64 + (seg & 3) * 16 + (row & 15)] = wv;
#pragma unroll
  for (int off = 8; off > 0; off >>= 1) csum += __shfl_xor(csum, off, 64);
  if (seg == 0) crow[row] = 32896.f * (float)csum;
}

// Kernel A v2 (R17 form): RK4 bookkeeping + s2T = transpose(M * y_stage).
// rhs sums FOUR aggp quarters (kB grid = 2048 blocks).
__global__ __launch_bounds__(256) void kA2(
    const float* __restrict__ y0, const float* __restrict__ bias,
    const float* __restrict__ M, const float* __restrict__ aggp,
    float* __restrict__ ybuf, float* __restrict__ racc,
    float* __restrict__ s2T, float* __restrict__ out,
    int stage, int step) {
  __shared__ float ystage[512];
  const int b = blockIdx.x >> 4, lg = blockIdx.x & 15, t = threadIdx.x;
  const float* ycur = ybuf + (step & 1) * 8192;
  float* ynext = ybuf + ((step + 1) & 1) * 8192;

  for (int i = t; i < 512; i += 256) {
    const int idx = b * 512 + i;
    const bool own = (i >> 5) == lg;
    float ys;
    if (stage == 0) {
      ys = y0[idx];
      if (own) ynext[idx] = ys;
    } else {
      const float r = bias[idx] - (aggp[idx] + aggp[8192 + idx] +
                                   aggp[16384 + idx] + aggp[24576 + idx]);
      const float yb = ycur[idx];
      if (stage == 1) {
        ys = fmaf(0.5f * DT, r, yb);
        if (own) racc[idx] = r;
      } else if (stage == 2) {
        ys = fmaf(0.5f * DT, r, yb);
        if (own) racc[idx] = racc[idx] + 2.f * r;
      } else if (stage == 3) {
        ys = fmaf(DT, r, yb);
        if (own) racc[idx] = racc[idx] + 2.f * r;
      } else {
        ys = yb + (DT / 6.f) * (racc[idx] + r);
        if (own) { ynext[idx] = ys; out[step * 8192 + idx] = ys; }
      }
    }
    ystage[i] = ys;
  }
  __syncthreads();

  const int g = t >> 5, u = t & 31;
  const int l = lg * 8 + g;
  const float* Mrow = M + l * 512;
  const int i0 = u * 16;
  float p = 0.f;
#pragma unroll
  for (int k = 0; k < 4; ++k) {
    const int off = ((u + k) & 3) << 2;
    const float4 mv = *(const float4*)(Mrow + i0 + off);
    const float4 yv = *(const float4*)(ystage + i0 + off);
    p = fmaf(mv.x, yv.x, p);
    p = fmaf(mv.y, yv.y, p);
    p = fmaf(mv.z, yv.z, p);
    p = fmaf(mv.w, yv.w, p);
  }
#pragma unroll
  for (int off = 16; off > 0; off >>= 1) p += __shfl_down(p, off, 32);
  if (u == 0) s2T[l * 16 + b] = p;
}

// Kernel B (i8 MFMA, 2048-block grid): both tiles' A-fragments are now
// prefetched BEFORE any MFMA (doubles in-flight k-bytes per wave — kB is
// Little's-law latency-bound), and the Gd (kl*sl) MFMA is dropped: its
// worst-case contribution is 2^21 quantized units = 7.6e-6 relative, three
// orders below the k-quant error. Everything else identical to R19.
__global__ __launch_bounds__(256) void kBi8(
    const i64x2* __restrict__ kF2,
    const float* __restrict__ adj, const float* __restrict__ s2T,
    const float* __restrict__ rowinv, const float* __restrict__ crow,
    float* __restrict__ aggp) {
  __shared__ __align__(8) signed char sqA[16][136];  // sh plane, [b][k]
  __shared__ __align__(8) signed char sqB[16][136];  // sm
  __shared__ __align__(8) signed char sqC[16][136];  // sl
  __shared__ float sred[16][16];
  __shared__ float scaleL[16], sinvLs[16], cbLs[16];
  __shared__ float part[64];
  const int t = threadIdx.x;
  const int b16 = t & 15, jg = t >> 4;

  // phase 1: per-b absmax of s2T[j][b]
  float mx = 0.f;
#pragma unroll
  for (int i = 0; i < 8; ++i)
    mx = fmaxf(mx, fabsf(s2T[(jg * 8 + i) * 16 + b16]));
  sred[jg][b16] = mx;
  __syncthreads();
  if (t < 16) {
    float m = 0.f;
#pragma unroll
    for (int g = 0; g < 16; ++g) m = fmaxf(m, sred[g][t]);
    scaleL[t] = m > 0.f ? 8388607.f / m : 0.f;
    sinvLs[t] = m > 0.f ? m / 8388607.f : 0.f;
  }
  __syncthreads();
  // phase 2: quantize s to 3 i8 planes (transposed [b][k]) + cb partials
  {
    const float sc = scaleL[b16];
    u64 pa = 0, pb = 0, pc = 0;
    int ps2 = 0, psm = 0, psl = 0;
#pragma unroll
    for (int i = 0; i < 8; ++i) {
      int q = (int)rintf(s2T[(jg * 8 + i) * 16 + b16] * sc);
      q = q > 8388607 ? 8388607 : (q < -8388607 ? -8388607 : q);  // i8 wrap guard
      const int h = q >> 16;
      const int m = ((q >> 8) & 255) - 128;
      const int lo = (q & 255) - 128;
      pa |= (u64)(unsigned char)(signed char)h << (8 * i);
      pb |= (u64)(unsigned char)(signed char)m << (8 * i);
      pc |= (u64)(unsigned char)(signed char)lo << (8 * i);
      ps2 += h; psm += m; psl += lo;
    }
    *(u64*)&sqA[b16][jg * 8] = pa;
    *(u64*)&sqB[b16][jg * 8] = pb;
    *(u64*)&sqC[b16][jg * 8] = pc;
    sred[jg][b16] = 8388608.f * (float)ps2 + 32768.f * (float)psm + 128.f * (float)psl;
  }
  __syncthreads();
  if (t < 16) {
    float s = 0.f;
#pragma unroll
    for (int g = 0; g < 16; ++g) s += sred[g][t];
    cbLs[t] = s + 538968064.f;   // + 128*32896*K (K=128)
  }
  __syncthreads();

  // B fragments: lane (b=lane&15, kg=lane>>4) holds 8 k-bytes per chunk.
  const int lane = t & 63, w = t >> 6;
  const int bb = lane & 15, kg = lane >> 4;
  i64 bA[4], bB[4], bC[4];
#pragma unroll
  for (int c = 0; c < 4; ++c) {
    const int kb = c * 32 + kg * 8;
    bA[c] = *(const i64*)&sqA[bb][kb];
    bB[c] = *(const i64*)&sqB[bb][kb];
    bC[c] = *(const i64*)&sqC[bb][kb];
  }
  const float sb = sinvLs[bb], cbb = cbLs[bb];

  const int rid0 = blockIdx.x * 128;      // 128 rows per block
  const int l = blockIdx.x >> 2;          // 4 blocks per l
  const int quarter = blockIdx.x & 3;

  // prefetch BOTH tiles' A-fragments before any MFMA (static indices)
  i64 ah0[4], al0[4], ah1[4], al1[4];
  {
    const size_t tile0 = (size_t)((rid0 + w * 32) >> 4);
#pragma unroll
    for (int c = 0; c < 4; ++c) {
      const i64x2 v = kF2[(tile0 * 4 + c) * 64 + lane];
      ah0[c] = v.x;
      al0[c] = v.y;
    }
#pragma unroll
    for (int c = 0; c < 4; ++c) {
      const i64x2 v = kF2[((tile0 + 1) * 4 + c) * 64 + lane];
      ah1[c] = v.x;
      al1[c] = v.y;
    }
  }

  float bacc = 0.f;
#pragma unroll
  for (int tt = 0; tt < 2; ++tt) {        // 2 tiles per wave
    const int ridT = rid0 + w * 32 + tt * 16;
    int4v Ga = {0, 0, 0, 0}, Gb = {0, 0, 0, 0}, Gc = {0, 0, 0, 0};
#pragma unroll
    for (int c = 0; c < 4; ++c) {
      const i64 ahc = tt == 0 ? ah0[c] : ah1[c];
      const i64 alc = tt == 0 ? al0[c] : al1[c];
      Ga = __builtin_amdgcn_mfma_i32_16x16x32_i8(ahc, bA[c], Ga, 0, 0, 0);
      Gb = __builtin_amdgcn_mfma_i32_16x16x32_i8(ahc, bB[c], Gb, 0, 0, 0);
      Gb = __builtin_amdgcn_mfma_i32_16x16x32_i8(alc, bA[c], Gb, 0, 0, 0);
      Gc = __builtin_amdgcn_mfma_i32_16x16x32_i8(ahc, bC[c], Gc, 0, 0, 0);
      Gc = __builtin_amdgcn_mfma_i32_16x16x32_i8(alc, bB[c], Gc, 0, 0, 0);
      // Gd (alc x bC) dropped: <= 2^21 quantized = 7.6e-6 relative
    }
    // epilogue: C/D row = kg*4 + reg, col = bb (verified layout)
    const int rbase = ridT + kg * 4;
    const float4 cr = *(const float4*)(crow + rbase);
    const float4 ri = *(const float4*)(rowinv + rbase);
    const float4 ad = *(const float4*)(adj + (size_t)bb * 262144 + rbase);
    const float crA[4] = {cr.x, cr.y, cr.z, cr.w};
    const float riA[4] = {ri.x, ri.y, ri.z, ri.w};
    const float adA[4] = {ad.x, ad.y, ad.z, ad.w};
    float ts = 0.f;
#pragma unroll
    for (int r = 0; r < 4; ++r) {
      const float dq = 16777216.f * (float)Ga[r] + 65536.f * (float)Gb[r] +
                       256.f * (float)Gc[r] + crA[r] + cbb;
      ts += adA[r] * fast_sin(dq * (riA[r] * sb));
    }
    ts += __shfl_xor(ts, 16, 64);
    ts += __shfl_xor(ts, 32, 64);
    bacc += ts;
  }
  if (lane < 16) part[w * 16 + lane] = bacc;
  __syncthreads();
  if (t < 16) {
    float ssum = part[t] + part[16 + t] + part[32 + t] + part[48 + t];
    aggp[quarter * 8192 + t * 512 + l] = ssum;   // aggp[quarter][b][l]
  }
}

// Zero quarters 2-3 of aggp (fp32 fallback path writes only halves 0-1).
__global__ __launch_bounds__(256) void kZeroTail(float* __restrict__ aggp) {
  aggp[16384 + blockIdx.x * 256 + threadIdx.x] = 0.f;
}

// Kernel B fallback (fp32 k2, R4 body) — only if ws_size can't hold planes.
__global__ __launch_bounds__(256) void kBf32(
    const float* __restrict__ k2, const float* __restrict__ adj,
    const float* __restrict__ s2T, float* __restrict__ aggp) {
  __shared__ float lk[256 * 36];
  __shared__ float part[64];
  const int t = threadIdx.x;
  const int rid0 = blockIdx.x * 256;
  const int rid = rid0 + t;
  const int l = rid0 >> 9;
  const int half = blockIdx.x & 1;

  float dot[16];
#pragma unroll
  for (int b = 0; b < 16; ++b) dot[b] = 0.f;

  for (int c = 0; c < 4; ++c) {
    __syncthreads();
#pragma unroll
    for (int k = 0; k < 8; ++k) {
      const int f = k * 256 + t, row = f >> 3, e = f & 7;
      const float4 v = *(const float4*)(k2 + (size_t)(rid0 + row) * 128 + c * 32 + e * 4);
      *(float4*)(lk + row * 36 + e * 4) = v;
    }
    __syncthreads();
    const float* myrow = lk + t * 36;
#pragma unroll
    for (int q = 0; q < 8; ++q) {
      const float4 kv = *(const float4*)(myrow + q * 4);
      f32x16 sa, sb, sc, sd;
      sload4(s2T + (c * 32 + q * 4) * 16, sa, sb, sc, sd);
#pragma unroll
      for (int b = 0; b < 16; ++b) dot[b] = fmaf(sa[b], kv.x, dot[b]);
#pragma unroll
      for (int b = 0; b < 16; ++b) dot[b] = fmaf(sb[b], kv.y, dot[b]);
#pragma unroll
      for (int b = 0; b < 16; ++b) dot[b] = fmaf(sc[b], kv.z, dot[b]);
#pragma unroll
      for (int b = 0; b < 16; ++b) dot[b] = fmaf(sd[b], kv.w, dot[b]);
    }
  }

#pragma unroll
  for (int b = 0; b < 16; ++b) {
    float v = adj[(size_t)b * 262144 + rid] * fast_sin(dot[b]);
#pragma unroll
    for (int off = 32; off > 0; off >>= 1) v += __shfl_down(v, off, 64);
    if ((t & 63) == 0) part[(t >> 6) * 16 + b] = v;
  }
  __syncthreads();
  if (t < 16) {
    float ssum = part[t] + part[16 + t] + part[32 + t] + part[48 + t];
    aggp[half * 8192 + t * 512 + l] = ssum;
  }
}

extern "C" void kernel_launch(void* const* d_in, const int* in_sizes, int n_in,
                              void* d_out, int out_size, void* d_ws, size_t ws_size,
                              hipStream_t stream) {
  const float* y0   = (const float*)d_in[0];  // [16,512]
  const float* bias = (const float*)d_in[1];  // [16,512,1]
  const float* adj  = (const float*)d_in[2];  // [16,512,512]
  const float* k0   = (const float*)d_in[3];  // [128,512,512]
  const float* k1   = (const float*)d_in[4];  // [128,512,128]
  const float* k2   = (const float*)d_in[5];  // [512,512,128]
  float* out = (float*)d_out;                 // [8,16,512] f32

  float* w      = (float*)d_ws;
  float* K0p    = w;                 // 131072 floats
  float* K1s    = w + 131072;        // 16384
  float* M      = w + 147456;        // 65536
  float* s2T    = w + 212992;        // 2048
  float* ybuf   = w + 215040;        // 16384
  float* racc   = w + 231424;        // 8192
  float* aggp   = w + 239616;        // 32768 (4 quarters x [16][512])
  float* rowinv = w + 272384;        // 262144
  float* crow   = w + 534528;        // 262144
  i64x2* kF2    = (i64x2*)(w + 796672);  // 64 MB interleaved i8 planes
  const bool useI8 =
      ws_size >= (size_t)796672 * 4 + (size_t)67108864;

  kPrep1<<<512, 256, 0, stream>>>(k0, K0p);
  kPrep2<<<64, 256, 0, stream>>>(k1, K1s);
  kPrep3<<<256, 256, 0, stream>>>(K0p, K1s, M);
  if (useI8) kConvRow<<<16384, 256, 0, stream>>>(k2, kF2, rowinv, crow);
  else kZeroTail<<<64, 256, 0, stream>>>(aggp);   // fallback writes halves only

  kA2<<<256, 256, 0, stream>>>(y0, bias, M, aggp, ybuf, racc, s2T, out, 0, -1);

  for (int step = 0; step < 8; ++step) {
    for (int stage = 1; stage <= 4; ++stage) {
      if (useI8)
        kBi8<<<2048, 256, 0, stream>>>(kF2, adj, s2T, rowinv, crow, aggp);
      else
        kBf32<<<1024, 256, 0, stream>>>(k2, adj, s2T, aggp);
      kA2<<<256, 256, 0, stream>>>(y0, bias, M, aggp, ybuf, racc, s2T, out, stage, step);
    }
  }
}

// Round 21
// 684.175 us; speedup vs baseline: 1.1958x; 1.0535x over previous
//
#include <hip/hip_runtime.h>
#include <hip/hip_bf16.h>

typedef int int4v __attribute__((ext_vector_type(4)));
typedef long long i64;
typedef long long i64x2 __attribute__((ext_vector_type(2)));
typedef unsigned long long u64;
typedef unsigned int u32;
typedef unsigned short u16;

#define DT 0.01f

// sin(x) with Cody-Waite reduction mod pi, accurate to ~2e-7 for |x| < ~6000.
__device__ __forceinline__ float fast_sin(float x) {
  const float INVPI = 0.3183098861837907f;
  float n = rintf(x * INVPI);
  int ni = (int)n;
  float r = fmaf(n, -3.140625f, x);
  r = fmaf(n, -9.6765358979e-4f, r);
  float s = r * r;
  float p = fmaf(s, -2.5052108e-8f, 2.7557319e-6f);
  p = fmaf(s, p, -1.9841270e-4f);
  p = fmaf(s, p, 8.3333333e-3f);
  p = fmaf(s, p, -1.6666667e-1f);
  float res = fmaf(r * s, p, r);
  return (ni & 1) ? -res : res;
}

typedef float f32x16 __attribute__((ext_vector_type(16)));
// (kept for the fp32 fallback kernel)
__device__ __forceinline__ void sload4(const float* p, f32x16& a, f32x16& b,
                                       f32x16& c, f32x16& d) {
  asm volatile(
      "s_load_dwordx16 %0, %4, 0\n\t"
      "s_load_dwordx16 %1, %4, 0x40\n\t"
      "s_load_dwordx16 %2, %4, 0x80\n\t"
      "s_load_dwordx16 %3, %4, 0xc0\n\t"
      "s_waitcnt lgkmcnt(0)"
      : "=s"(a), "=s"(b), "=s"(c), "=s"(d)
      : "s"(p));
}

// K0 partial column sums (m split in 2 halves for occupancy).
__global__ __launch_bounds__(256) void kPrep1(const float* __restrict__ k0,
                                              float* __restrict__ K0p) {
  const int id = (blockIdx.x & 255) * 256 + threadIdx.x;
  const int p = blockIdx.x >> 8;
  const int h = id >> 9, j = id & 511;
  const float* q = k0 + (size_t)h * 262144 + (size_t)(p * 256) * 512 + j;
  float s = 0.f;
  for (int m = 0; m < 256; ++m) s += q[(size_t)m * 512];
  K0p[p * 65536 + id] = s;
}

// K1s[h,j] = sum_m k1[h,m,j]
__global__ __launch_bounds__(256) void kPrep2(const float* __restrict__ k1,
                                              float* __restrict__ K1s) {
  int t = blockIdx.x * 256 + threadIdx.x;
  int h = t >> 7, j = t & 127;
  const float* p = k1 + (size_t)h * 65536 + j;
  float s = 0.f;
  for (int m = 0; m < 512; ++m) s += p[(size_t)m * 128];
  K1s[t] = s;
}

// M[l,j] = sum_h K1s[l,h] * (K0pA[h,j] + K0pB[h,j])
__global__ __launch_bounds__(256) void kPrep3(const float* __restrict__ K0p,
                                              const float* __restrict__ K1s,
                                              float* __restrict__ M) {
  int t = blockIdx.x * 256 + threadIdx.x;
  int l = t >> 9, j = t & 511;
  float s = 0.f;
#pragma unroll 8
  for (int h = 0; h < 128; ++h)
    s = fmaf(K1s[l * 128 + h], K0p[h * 512 + j] + K0p[65536 + h * 512 + j], s);
  M[t] = s;
}

// Per-row int16 quantization of k2 into interleaved i8 planes in MFMA
// fragment order (see R17). q cannot round past 32767 (32767*2eps << 0.5).
__global__ __launch_bounds__(256) void kConvRow(const float* __restrict__ k2,
                                                i64x2* __restrict__ kF2,
                                                float* __restrict__ rowinv,
                                                float* __restrict__ crow) {
  const int t = threadIdx.x;
  const int row = blockIdx.x * 16 + (t >> 4);
  const int seg = t & 15;
  const float* src = k2 + (size_t)row * 128 + seg * 8;
  const float4 a = *(const float4*)(src);
  const float4 b = *(const float4*)(src + 4);
  float m = fmaxf(fmaxf(fmaxf(fabsf(a.x), fabsf(a.y)), fmaxf(fabsf(a.z), fabsf(a.w))),
                  fmaxf(fmaxf(fabsf(b.x), fabsf(b.y)), fmaxf(fabsf(b.z), fabsf(b.w))));
#pragma unroll
  for (int off = 8; off > 0; off >>= 1) m = fmaxf(m, __shfl_xor(m, off, 64));
  const float scale = m > 0.f ? 32767.0f / m : 0.f;
  if (seg == 0) rowinv[row] = m > 0.f ? m / 32767.0f : 0.f;
  const float v[8] = {a.x, a.y, a.z, a.w, b.x, b.y, b.z, b.w};
  u64 ph = 0, pl = 0;
  int csum = 0;
#pragma unroll
  for (int i = 0; i < 8; ++i) {
    const int q = (int)rintf(v[i] * scale);
    const int kh = q >> 8;
    const int kl = (q & 255) - 128;
    ph |= (u64)(unsigned char)(signed char)kh << (8 * i);
    pl |= (u64)(unsigned char)(signed char)kl << (8 * i);
    csum += q - 128;
  }
  i64x2 wv;
  wv.x = (i64)ph;
  wv.y = (i64)pl;
  kF2[((size_t)(row >> 4) * 4 + (seg >> 2)) * 64 + (seg & 3) * 16 + (row & 15)] = wv;
#pragma unroll
  for (int off = 8; off > 0; off >>= 1) csum += __shfl_xor(csum, off, 64);
  if (seg == 0) crow[row] = 32896.f * (float)csum;
}

// adj f32 -> u16 fixed point (adj in [0,1)): absolute error <= 7.6e-6.
// 8 elements/thread, 4194304 elements total.
__global__ __launch_bounds__(256) void kConvAdj(const float* __restrict__ adj,
                                                u16* __restrict__ adjq) {
  const size_t i = ((size_t)blockIdx.x * 256 + threadIdx.x) * 8;
  const float4 a = *(const float4*)(adj + i);
  const float4 b = *(const float4*)(adj + i + 4);
  ushort4 o0, o1;
  o0.x = (u16)rintf(a.x * 65535.f);
  o0.y = (u16)rintf(a.y * 65535.f);
  o0.z = (u16)rintf(a.z * 65535.f);
  o0.w = (u16)rintf(a.w * 65535.f);
  o1.x = (u16)rintf(b.x * 65535.f);
  o1.y = (u16)rintf(b.y * 65535.f);
  o1.z = (u16)rintf(b.z * 65535.f);
  o1.w = (u16)rintf(b.w * 65535.f);
  *(ushort4*)(adjq + i) = o0;
  *(ushort4*)(adjq + i + 4) = o1;
}

// Kernel A v2 (R17 form): RK4 bookkeeping + s2T = transpose(M * y_stage).
// rhs sums FOUR aggp quarters (kB grid = 2048 blocks).
__global__ __launch_bounds__(256) void kA2(
    const float* __restrict__ y0, const float* __restrict__ bias,
    const float* __restrict__ M, const float* __restrict__ aggp,
    float* __restrict__ ybuf, float* __restrict__ racc,
    float* __restrict__ s2T, float* __restrict__ out,
    int stage, int step) {
  __shared__ float ystage[512];
  const int b = blockIdx.x >> 4, lg = blockIdx.x & 15, t = threadIdx.x;
  const float* ycur = ybuf + (step & 1) * 8192;
  float* ynext = ybuf + ((step + 1) & 1) * 8192;

  for (int i = t; i < 512; i += 256) {
    const int idx = b * 512 + i;
    const bool own = (i >> 5) == lg;
    float ys;
    if (stage == 0) {
      ys = y0[idx];
      if (own) ynext[idx] = ys;
    } else {
      const float r = bias[idx] - (aggp[idx] + aggp[8192 + idx] +
                                   aggp[16384 + idx] + aggp[24576 + idx]);
      const float yb = ycur[idx];
      if (stage == 1) {
        ys = fmaf(0.5f * DT, r, yb);
        if (own) racc[idx] = r;
      } else if (stage == 2) {
        ys = fmaf(0.5f * DT, r, yb);
        if (own) racc[idx] = racc[idx] + 2.f * r;
      } else if (stage == 3) {
        ys = fmaf(DT, r, yb);
        if (own) racc[idx] = racc[idx] + 2.f * r;
      } else {
        ys = yb + (DT / 6.f) * (racc[idx] + r);
        if (own) { ynext[idx] = ys; out[step * 8192 + idx] = ys; }
      }
    }
    ystage[i] = ys;
  }
  __syncthreads();

  const int g = t >> 5, u = t & 31;
  const int l = lg * 8 + g;
  const float* Mrow = M + l * 512;
  const int i0 = u * 16;
  float p = 0.f;
#pragma unroll
  for (int k = 0; k < 4; ++k) {
    const int off = ((u + k) & 3) << 2;
    const float4 mv = *(const float4*)(Mrow + i0 + off);
    const float4 yv = *(const float4*)(ystage + i0 + off);
    p = fmaf(mv.x, yv.x, p);
    p = fmaf(mv.y, yv.y, p);
    p = fmaf(mv.z, yv.z, p);
    p = fmaf(mv.w, yv.w, p);
  }
#pragma unroll
  for (int off = 16; off > 0; off >>= 1) p += __shfl_down(p, off, 32);
  if (u == 0) s2T[l * 16 + b] = p;
}

// Kernel B (i8 MFMA, 2048-block grid): A-fragments AND u16 adj for both
// tiles prefetched before any MFMA (kB is Little's-law latency-bound —
// more in-flight bytes per wave). adj u16 halves its stream (17->8.5 MB);
// the 1/65535 dequant folds into the single per-wave part write (sums
// < 2^24, exact). Gd dropped (7.6e-6 relative, R20). Math otherwise R19.
__global__ __launch_bounds__(256) void kBi8(
    const i64x2* __restrict__ kF2,
    const u16* __restrict__ adjq, const float* __restrict__ s2T,
    const float* __restrict__ rowinv, const float* __restrict__ crow,
    float* __restrict__ aggp) {
  __shared__ __align__(8) signed char sqA[16][136];  // sh plane, [b][k]
  __shared__ __align__(8) signed char sqB[16][136];  // sm
  __shared__ __align__(8) signed char sqC[16][136];  // sl
  __shared__ float sred[16][16];
  __shared__ float scaleL[16], sinvLs[16], cbLs[16];
  __shared__ float part[64];
  const int t = threadIdx.x;
  const int b16 = t & 15, jg = t >> 4;

  // phase 1: per-b absmax of s2T[j][b]
  float mx = 0.f;
#pragma unroll
  for (int i = 0; i < 8; ++i)
    mx = fmaxf(mx, fabsf(s2T[(jg * 8 + i) * 16 + b16]));
  sred[jg][b16] = mx;
  __syncthreads();
  if (t < 16) {
    float m = 0.f;
#pragma unroll
    for (int g = 0; g < 16; ++g) m = fmaxf(m, sred[g][t]);
    scaleL[t] = m > 0.f ? 8388607.f / m : 0.f;
    sinvLs[t] = m > 0.f ? m / 8388607.f : 0.f;
  }
  __syncthreads();
  // phase 2: quantize s to 3 i8 planes (transposed [b][k]) + cb partials
  {
    const float sc = scaleL[b16];
    u64 pa = 0, pb = 0, pc = 0;
    int ps2 = 0, psm = 0, psl = 0;
#pragma unroll
    for (int i = 0; i < 8; ++i) {
      int q = (int)rintf(s2T[(jg * 8 + i) * 16 + b16] * sc);
      q = q > 8388607 ? 8388607 : (q < -8388607 ? -8388607 : q);  // i8 wrap guard
      const int h = q >> 16;
      const int m = ((q >> 8) & 255) - 128;
      const int lo = (q & 255) - 128;
      pa |= (u64)(unsigned char)(signed char)h << (8 * i);
      pb |= (u64)(unsigned char)(signed char)m << (8 * i);
      pc |= (u64)(unsigned char)(signed char)lo << (8 * i);
      ps2 += h; psm += m; psl += lo;
    }
    *(u64*)&sqA[b16][jg * 8] = pa;
    *(u64*)&sqB[b16][jg * 8] = pb;
    *(u64*)&sqC[b16][jg * 8] = pc;
    sred[jg][b16] = 8388608.f * (float)ps2 + 32768.f * (float)psm + 128.f * (float)psl;
  }
  __syncthreads();
  if (t < 16) {
    float s = 0.f;
#pragma unroll
    for (int g = 0; g < 16; ++g) s += sred[g][t];
    cbLs[t] = s + 538968064.f;   // + 128*32896*K (K=128)
  }
  __syncthreads();

  // B fragments: lane (b=lane&15, kg=lane>>4) holds 8 k-bytes per chunk.
  const int lane = t & 63, w = t >> 6;
  const int bb = lane & 15, kg = lane >> 4;
  i64 bA[4], bB[4], bC[4];
#pragma unroll
  for (int c = 0; c < 4; ++c) {
    const int kb = c * 32 + kg * 8;
    bA[c] = *(const i64*)&sqA[bb][kb];
    bB[c] = *(const i64*)&sqB[bb][kb];
    bC[c] = *(const i64*)&sqC[bb][kb];
  }
  const float sb = sinvLs[bb], cbb = cbLs[bb];

  const int rid0 = blockIdx.x * 128;      // 128 rows per block
  const int l = blockIdx.x >> 2;          // 4 blocks per l
  const int quarter = blockIdx.x & 3;

  // prefetch BOTH tiles' A-fragments + u16 adj before any MFMA
  i64 ah0[4], al0[4], ah1[4], al1[4];
  ushort4 adq0, adq1;
  {
    const int r0 = rid0 + w * 32;
    const size_t tile0 = (size_t)(r0 >> 4);
#pragma unroll
    for (int c = 0; c < 4; ++c) {
      const i64x2 v = kF2[(tile0 * 4 + c) * 64 + lane];
      ah0[c] = v.x;
      al0[c] = v.y;
    }
#pragma unroll
    for (int c = 0; c < 4; ++c) {
      const i64x2 v = kF2[((tile0 + 1) * 4 + c) * 64 + lane];
      ah1[c] = v.x;
      al1[c] = v.y;
    }
    adq0 = *(const ushort4*)(adjq + (size_t)bb * 262144 + r0 + kg * 4);
    adq1 = *(const ushort4*)(adjq + (size_t)bb * 262144 + r0 + 16 + kg * 4);
  }

  float bacc = 0.f;
#pragma unroll
  for (int tt = 0; tt < 2; ++tt) {        // 2 tiles per wave
    const int ridT = rid0 + w * 32 + tt * 16;
    int4v Ga = {0, 0, 0, 0}, Gb = {0, 0, 0, 0}, Gc = {0, 0, 0, 0};
#pragma unroll
    for (int c = 0; c < 4; ++c) {
      const i64 ahc = tt == 0 ? ah0[c] : ah1[c];
      const i64 alc = tt == 0 ? al0[c] : al1[c];
      Ga = __builtin_amdgcn_mfma_i32_16x16x32_i8(ahc, bA[c], Ga, 0, 0, 0);
      Gb = __builtin_amdgcn_mfma_i32_16x16x32_i8(ahc, bB[c], Gb, 0, 0, 0);
      Gb = __builtin_amdgcn_mfma_i32_16x16x32_i8(alc, bA[c], Gb, 0, 0, 0);
      Gc = __builtin_amdgcn_mfma_i32_16x16x32_i8(ahc, bC[c], Gc, 0, 0, 0);
      Gc = __builtin_amdgcn_mfma_i32_16x16x32_i8(alc, bB[c], Gc, 0, 0, 0);
    }
    // epilogue: C/D row = kg*4 + reg, col = bb (verified layout)
    const int rbase = ridT + kg * 4;
    const float4 cr = *(const float4*)(crow + rbase);
    const float4 ri = *(const float4*)(rowinv + rbase);
    const ushort4 adq = tt == 0 ? adq0 : adq1;
    const float crA[4] = {cr.x, cr.y, cr.z, cr.w};
    const float riA[4] = {ri.x, ri.y, ri.z, ri.w};
    const float adA[4] = {(float)adq.x, (float)adq.y, (float)adq.z, (float)adq.w};
    float ts = 0.f;
#pragma unroll
    for (int r = 0; r < 4; ++r) {
      const float dq = 16777216.f * (float)Ga[r] + 65536.f * (float)Gb[r] +
                       256.f * (float)Gc[r] + crA[r] + cbb;
      ts += adA[r] * fast_sin(dq * (riA[r] * sb));
    }
    ts += __shfl_xor(ts, 16, 64);
    ts += __shfl_xor(ts, 32, 64);
    bacc += ts;
  }
  if (lane < 16) part[w * 16 + lane] = bacc * (1.0f / 65535.f);
  __syncthreads();
  if (t < 16) {
    float ssum = part[t] + part[16 + t] + part[32 + t] + part[48 + t];
    aggp[quarter * 8192 + t * 512 + l] = ssum;   // aggp[quarter][b][l]
  }
}

// Zero quarters 2-3 of aggp (fp32 fallback path writes only halves 0-1).
__global__ __launch_bounds__(256) void kZeroTail(float* __restrict__ aggp) {
  aggp[16384 + blockIdx.x * 256 + threadIdx.x] = 0.f;
}

// Kernel B fallback (fp32 k2, R4 body) — only if ws_size can't hold planes.
__global__ __launch_bounds__(256) void kBf32(
    const float* __restrict__ k2, const float* __restrict__ adj,
    const float* __restrict__ s2T, float* __restrict__ aggp) {
  __shared__ float lk[256 * 36];
  __shared__ float part[64];
  const int t = threadIdx.x;
  const int rid0 = blockIdx.x * 256;
  const int rid = rid0 + t;
  const int l = rid0 >> 9;
  const int half = blockIdx.x & 1;

  float dot[16];
#pragma unroll
  for (int b = 0; b < 16; ++b) dot[b] = 0.f;

  for (int c = 0; c < 4; ++c) {
    __syncthreads();
#pragma unroll
    for (int k = 0; k < 8; ++k) {
      const int f = k * 256 + t, row = f >> 3, e = f & 7;
      const float4 v = *(const float4*)(k2 + (size_t)(rid0 + row) * 128 + c * 32 + e * 4);
      *(float4*)(lk + row * 36 + e * 4) = v;
    }
    __syncthreads();
    const float* myrow = lk + t * 36;
#pragma unroll
    for (int q = 0; q < 8; ++q) {
      const float4 kv = *(const float4*)(myrow + q * 4);
      f32x16 sa, sb, sc, sd;
      sload4(s2T + (c * 32 + q * 4) * 16, sa, sb, sc, sd);
#pragma unroll
      for (int b = 0; b < 16; ++b) dot[b] = fmaf(sa[b], kv.x, dot[b]);
#pragma unroll
      for (int b = 0; b < 16; ++b) dot[b] = fmaf(sb[b], kv.y, dot[b]);
#pragma unroll
      for (int b = 0; b < 16; ++b) dot[b] = fmaf(sc[b], kv.z, dot[b]);
#pragma unroll
      for (int b = 0; b < 16; ++b) dot[b] = fmaf(sd[b], kv.w, dot[b]);
    }
  }

#pragma unroll
  for (int b = 0; b < 16; ++b) {
    float v = adj[(size_t)b * 262144 + rid] * fast_sin(dot[b]);
#pragma unroll
    for (int off = 32; off > 0; off >>= 1) v += __shfl_down(v, off, 64);
    if ((t & 63) == 0) part[(t >> 6) * 16 + b] = v;
  }
  __syncthreads();
  if (t < 16) {
    float ssum = part[t] + part[16 + t] + part[32 + t] + part[48 + t];
    aggp[half * 8192 + t * 512 + l] = ssum;
  }
}

extern "C" void kernel_launch(void* const* d_in, const int* in_sizes, int n_in,
                              void* d_out, int out_size, void* d_ws, size_t ws_size,
                              hipStream_t stream) {
  const float* y0   = (const float*)d_in[0];  // [16,512]
  const float* bias = (const float*)d_in[1];  // [16,512,1]
  const float* adj  = (const float*)d_in[2];  // [16,512,512]
  const float* k0   = (const float*)d_in[3];  // [128,512,512]
  const float* k1   = (const float*)d_in[4];  // [128,512,128]
  const float* k2   = (const float*)d_in[5];  // [512,512,128]
  float* out = (float*)d_out;                 // [8,16,512] f32

  float* w      = (float*)d_ws;
  float* K0p    = w;                 // 131072 floats
  float* K1s    = w + 131072;        // 16384
  float* M      = w + 147456;        // 65536
  float* s2T    = w + 212992;        // 2048
  float* ybuf   = w + 215040;        // 16384
  float* racc   = w + 231424;        // 8192
  float* aggp   = w + 239616;        // 32768 (4 quarters x [16][512])
  float* rowinv = w + 272384;        // 262144
  float* crow   = w + 534528;        // 262144
  i64x2* kF2    = (i64x2*)(w + 796672);             // 64 MB i8 planes
  u16*   adjq   = (u16*)((char*)kF2 + 67108864);    // 8.5 MB u16 adj
  const bool useI8 =
      ws_size >= (size_t)796672 * 4 + (size_t)67108864 + (size_t)8388608;

  kPrep1<<<512, 256, 0, stream>>>(k0, K0p);
  kPrep2<<<64, 256, 0, stream>>>(k1, K1s);
  kPrep3<<<256, 256, 0, stream>>>(K0p, K1s, M);
  if (useI8) {
    kConvRow<<<16384, 256, 0, stream>>>(k2, kF2, rowinv, crow);
    kConvAdj<<<2048, 256, 0, stream>>>(adj, adjq);
  } else {
    kZeroTail<<<64, 256, 0, stream>>>(aggp);   // fallback writes halves only
  }

  kA2<<<256, 256, 0, stream>>>(y0, bias, M, aggp, ybuf, racc, s2T, out, 0, -1);

  for (int step = 0; step < 8; ++step) {
    for (int stage = 1; stage <= 4; ++stage) {
      if (useI8)
        kBi8<<<2048, 256, 0, stream>>>(kF2, adjq, s2T, rowinv, crow, aggp);
      else
        kBf32<<<1024, 256, 0, stream>>>(k2, adj, s2T, aggp);
      kA2<<<256, 256, 0, stream>>>(y0, bias, M, aggp, ybuf, racc, s2T, out, stage, step);
    }
  }
}

// Round 22
// 662.355 us; speedup vs baseline: 1.2352x; 1.0329x over previous
//
#include <hip/hip_runtime.h>
#include <hip/hip_bf16.h>

typedef int int4v __attribute__((ext_vector_type(4)));
typedef long long i64;
typedef long long i64x2 __attribute__((ext_vector_type(2)));
typedef unsigned long long u64;
typedef unsigned int u32;
typedef unsigned short u16;

#define DT 0.01f

// sin(x) with Cody-Waite reduction mod pi, accurate to ~2e-7 for |x| < ~6000.
__device__ __forceinline__ float fast_sin(float x) {
  const float INVPI = 0.3183098861837907f;
  float n = rintf(x * INVPI);
  int ni = (int)n;
  float r = fmaf(n, -3.140625f, x);
  r = fmaf(n, -9.6765358979e-4f, r);
  float s = r * r;
  float p = fmaf(s, -2.5052108e-8f, 2.7557319e-6f);
  p = fmaf(s, p, -1.9841270e-4f);
  p = fmaf(s, p, 8.3333333e-3f);
  p = fmaf(s, p, -1.6666667e-1f);
  float res = fmaf(r * s, p, r);
  return (ni & 1) ? -res : res;
}

typedef float f32x16 __attribute__((ext_vector_type(16)));
// (kept for the fp32 fallback kernel)
__device__ __forceinline__ void sload4(const float* p, f32x16& a, f32x16& b,
                                       f32x16& c, f32x16& d) {
  asm volatile(
      "s_load_dwordx16 %0, %4, 0\n\t"
      "s_load_dwordx16 %1, %4, 0x40\n\t"
      "s_load_dwordx16 %2, %4, 0x80\n\t"
      "s_load_dwordx16 %3, %4, 0xc0\n\t"
      "s_waitcnt lgkmcnt(0)"
      : "=s"(a), "=s"(b), "=s"(c), "=s"(d)
      : "s"(p));
}

// K0 partial column sums (m split in 2 halves for occupancy).
__global__ __launch_bounds__(256) void kPrep1(const float* __restrict__ k0,
                                              float* __restrict__ K0p) {
  const int id = (blockIdx.x & 255) * 256 + threadIdx.x;
  const int p = blockIdx.x >> 8;
  const int h = id >> 9, j = id & 511;
  const float* q = k0 + (size_t)h * 262144 + (size_t)(p * 256) * 512 + j;
  float s = 0.f;
  for (int m = 0; m < 256; ++m) s += q[(size_t)m * 512];
  K0p[p * 65536 + id] = s;
}

// K1s[h,j] = sum_m k1[h,m,j]
__global__ __launch_bounds__(256) void kPrep2(const float* __restrict__ k1,
                                              float* __restrict__ K1s) {
  int t = blockIdx.x * 256 + threadIdx.x;
  int h = t >> 7, j = t & 127;
  const float* p = k1 + (size_t)h * 65536 + j;
  float s = 0.f;
  for (int m = 0; m < 512; ++m) s += p[(size_t)m * 128];
  K1s[t] = s;
}

// M[l,j] = sum_h K1s[l,h] * (K0pA[h,j] + K0pB[h,j])
__global__ __launch_bounds__(256) void kPrep3(const float* __restrict__ K0p,
                                              const float* __restrict__ K1s,
                                              float* __restrict__ M) {
  int t = blockIdx.x * 256 + threadIdx.x;
  int l = t >> 9, j = t & 511;
  float s = 0.f;
#pragma unroll 8
  for (int h = 0; h < 128; ++h)
    s = fmaf(K1s[l * 128 + h], K0p[h * 512 + j] + K0p[65536 + h * 512 + j], s);
  M[t] = s;
}

// Per-row int16 quantization of k2 into interleaved i8 planes in MFMA
// fragment order (see R17). q cannot round past 32767 (32767*2eps << 0.5).
__global__ __launch_bounds__(256) void kConvRow(const float* __restrict__ k2,
                                                i64x2* __restrict__ kF2,
                                                float* __restrict__ rowinv,
                                                float* __restrict__ crow) {
  const int t = threadIdx.x;
  const int row = blockIdx.x * 16 + (t >> 4);
  const int seg = t & 15;
  const float* src = k2 + (size_t)row * 128 + seg * 8;
  const float4 a = *(const float4*)(src);
  const float4 b = *(const float4*)(src + 4);
  float m = fmaxf(fmaxf(fmaxf(fabsf(a.x), fabsf(a.y)), fmaxf(fabsf(a.z), fabsf(a.w))),
                  fmaxf(fmaxf(fabsf(b.x), fabsf(b.y)), fmaxf(fabsf(b.z), fabsf(b.w))));
#pragma unroll
  for (int off = 8; off > 0; off >>= 1) m = fmaxf(m, __shfl_xor(m, off, 64));
  const float scale = m > 0.f ? 32767.0f / m : 0.f;
  if (seg == 0) rowinv[row] = m > 0.f ? m / 32767.0f : 0.f;
  const float v[8] = {a.x, a.y, a.z, a.w, b.x, b.y, b.z, b.w};
  u64 ph = 0, pl = 0;
  int csum = 0;
#pragma unroll
  for (int i = 0; i < 8; ++i) {
    const int q = (int)rintf(v[i] * scale);
    const int kh = q >> 8;
    const int kl = (q & 255) - 128;
    ph |= (u64)(unsigned char)(signed char)kh << (8 * i);
    pl |= (u64)(unsigned char)(signed char)kl << (8 * i);
    csum += q - 128;
  }
  i64x2 wv;
  wv.x = (i64)ph;
  wv.y = (i64)pl;
  kF2[((size_t)(row >> 4) * 4 + (seg >> 2)) * 64 + (seg & 3) * 16 + (row & 15)] = wv;
#pragma unroll
  for (int off = 8; off > 0; off >>= 1) csum += __shfl_xor(csum, off, 64);
  if (seg == 0) crow[row] = 32896.f * (float)csum;
}

// adj f32 -> u16 fixed point (adj in [0,1)): absolute error <= 7.6e-6.
__global__ __launch_bounds__(256) void kConvAdj(const float* __restrict__ adj,
                                                u16* __restrict__ adjq) {
  const size_t i = ((size_t)blockIdx.x * 256 + threadIdx.x) * 8;
  const float4 a = *(const float4*)(adj + i);
  const float4 b = *(const float4*)(adj + i + 4);
  ushort4 o0, o1;
  o0.x = (u16)rintf(a.x * 65535.f);
  o0.y = (u16)rintf(a.y * 65535.f);
  o0.z = (u16)rintf(a.z * 65535.f);
  o0.w = (u16)rintf(a.w * 65535.f);
  o1.x = (u16)rintf(b.x * 65535.f);
  o1.y = (u16)rintf(b.y * 65535.f);
  o1.z = (u16)rintf(b.z * 65535.f);
  o1.w = (u16)rintf(b.w * 65535.f);
  *(ushort4*)(adjq + i) = o0;
  *(ushort4*)(adjq + i + 4) = o1;
}

// Kernel A v2 (R17 form): RK4 bookkeeping + s2T = transpose(M * y_stage).
// rhs sums FOUR aggp quarters (kB grid = 2048 blocks).
__global__ __launch_bounds__(256) void kA2(
    const float* __restrict__ y0, const float* __restrict__ bias,
    const float* __restrict__ M, const float* __restrict__ aggp,
    float* __restrict__ ybuf, float* __restrict__ racc,
    float* __restrict__ s2T, float* __restrict__ out,
    int stage, int step) {
  __shared__ float ystage[512];
  const int b = blockIdx.x >> 4, lg = blockIdx.x & 15, t = threadIdx.x;
  const float* ycur = ybuf + (step & 1) * 8192;
  float* ynext = ybuf + ((step + 1) & 1) * 8192;

  for (int i = t; i < 512; i += 256) {
    const int idx = b * 512 + i;
    const bool own = (i >> 5) == lg;
    float ys;
    if (stage == 0) {
      ys = y0[idx];
      if (own) ynext[idx] = ys;
    } else {
      const float r = bias[idx] - (aggp[idx] + aggp[8192 + idx] +
                                   aggp[16384 + idx] + aggp[24576 + idx]);
      const float yb = ycur[idx];
      if (stage == 1) {
        ys = fmaf(0.5f * DT, r, yb);
        if (own) racc[idx] = r;
      } else if (stage == 2) {
        ys = fmaf(0.5f * DT, r, yb);
        if (own) racc[idx] = racc[idx] + 2.f * r;
      } else if (stage == 3) {
        ys = fmaf(DT, r, yb);
        if (own) racc[idx] = racc[idx] + 2.f * r;
      } else {
        ys = yb + (DT / 6.f) * (racc[idx] + r);
        if (own) { ynext[idx] = ys; out[step * 8192 + idx] = ys; }
      }
    }
    ystage[i] = ys;
  }
  __syncthreads();

  const int g = t >> 5, u = t & 31;
  const int l = lg * 8 + g;
  const float* Mrow = M + l * 512;
  const int i0 = u * 16;
  float p = 0.f;
#pragma unroll
  for (int k = 0; k < 4; ++k) {
    const int off = ((u + k) & 3) << 2;
    const float4 mv = *(const float4*)(Mrow + i0 + off);
    const float4 yv = *(const float4*)(ystage + i0 + off);
    p = fmaf(mv.x, yv.x, p);
    p = fmaf(mv.y, yv.y, p);
    p = fmaf(mv.z, yv.z, p);
    p = fmaf(mv.w, yv.w, p);
  }
#pragma unroll
  for (int off = 16; off > 0; off >>= 1) p += __shfl_down(p, off, 32);
  if (u == 0) s2T[l * 16 + b] = p;
}

// Kernel B (i8 MFMA, 2048-block grid): the A-fragment + adjq prefetch (10
// global loads, addresses depend only on blockIdx/lane) is now issued at
// the VERY TOP of the kernel — its ~600ns latency flies under the whole
// quant preamble (s2T loads + LDS + 4 barriers), and the first barrier's
// vmcnt(0) drain lands after the data had the preamble to arrive. Math
// byte-identical to R21 (absmax 0.05273438).
__global__ __launch_bounds__(256) void kBi8(
    const i64x2* __restrict__ kF2,
    const u16* __restrict__ adjq, const float* __restrict__ s2T,
    const float* __restrict__ rowinv, const float* __restrict__ crow,
    float* __restrict__ aggp) {
  __shared__ __align__(8) signed char sqA[16][136];  // sh plane, [b][k]
  __shared__ __align__(8) signed char sqB[16][136];  // sm
  __shared__ __align__(8) signed char sqC[16][136];  // sl
  __shared__ float sred[16][16];
  __shared__ float scaleL[16], sinvLs[16], cbLs[16];
  __shared__ float part[64];
  const int t = threadIdx.x;
  const int b16 = t & 15, jg = t >> 4;
  const int lane = t & 63, w = t >> 6;
  const int bb = lane & 15, kg = lane >> 4;
  const int rid0 = blockIdx.x * 128;      // 128 rows per block
  const int l = blockIdx.x >> 2;          // 4 blocks per l
  const int quarter = blockIdx.x & 3;

  // ---- prefetch BOTH tiles' A-fragments + u16 adj FIRST (block-static
  // addresses; latency hides under the whole quant preamble below) ----
  i64 ah0[4], al0[4], ah1[4], al1[4];
  ushort4 adq0, adq1;
  {
    const int r0 = rid0 + w * 32;
    const size_t tile0 = (size_t)(r0 >> 4);
#pragma unroll
    for (int c = 0; c < 4; ++c) {
      const i64x2 v = kF2[(tile0 * 4 + c) * 64 + lane];
      ah0[c] = v.x;
      al0[c] = v.y;
    }
#pragma unroll
    for (int c = 0; c < 4; ++c) {
      const i64x2 v = kF2[((tile0 + 1) * 4 + c) * 64 + lane];
      ah1[c] = v.x;
      al1[c] = v.y;
    }
    adq0 = *(const ushort4*)(adjq + (size_t)bb * 262144 + r0 + kg * 4);
    adq1 = *(const ushort4*)(adjq + (size_t)bb * 262144 + r0 + 16 + kg * 4);
  }

  // phase 1: per-b absmax of s2T[j][b]
  float mx = 0.f;
#pragma unroll
  for (int i = 0; i < 8; ++i)
    mx = fmaxf(mx, fabsf(s2T[(jg * 8 + i) * 16 + b16]));
  sred[jg][b16] = mx;
  __syncthreads();
  if (t < 16) {
    float m = 0.f;
#pragma unroll
    for (int g = 0; g < 16; ++g) m = fmaxf(m, sred[g][t]);
    scaleL[t] = m > 0.f ? 8388607.f / m : 0.f;
    sinvLs[t] = m > 0.f ? m / 8388607.f : 0.f;
  }
  __syncthreads();
  // phase 2: quantize s to 3 i8 planes (transposed [b][k]) + cb partials
  {
    const float sc = scaleL[b16];
    u64 pa = 0, pb = 0, pc = 0;
    int ps2 = 0, psm = 0, psl = 0;
#pragma unroll
    for (int i = 0; i < 8; ++i) {
      int q = (int)rintf(s2T[(jg * 8 + i) * 16 + b16] * sc);
      q = q > 8388607 ? 8388607 : (q < -8388607 ? -8388607 : q);  // i8 wrap guard
      const int h = q >> 16;
      const int m = ((q >> 8) & 255) - 128;
      const int lo = (q & 255) - 128;
      pa |= (u64)(unsigned char)(signed char)h << (8 * i);
      pb |= (u64)(unsigned char)(signed char)m << (8 * i);
      pc |= (u64)(unsigned char)(signed char)lo << (8 * i);
      ps2 += h; psm += m; psl += lo;
    }
    *(u64*)&sqA[b16][jg * 8] = pa;
    *(u64*)&sqB[b16][jg * 8] = pb;
    *(u64*)&sqC[b16][jg * 8] = pc;
    sred[jg][b16] = 8388608.f * (float)ps2 + 32768.f * (float)psm + 128.f * (float)psl;
  }
  __syncthreads();
  if (t < 16) {
    float s = 0.f;
#pragma unroll
    for (int g = 0; g < 16; ++g) s += sred[g][t];
    cbLs[t] = s + 538968064.f;   // + 128*32896*K (K=128)
  }
  __syncthreads();

  // B fragments: lane (b=lane&15, kg=lane>>4) holds 8 k-bytes per chunk.
  i64 bA[4], bB[4], bC[4];
#pragma unroll
  for (int c = 0; c < 4; ++c) {
    const int kb = c * 32 + kg * 8;
    bA[c] = *(const i64*)&sqA[bb][kb];
    bB[c] = *(const i64*)&sqB[bb][kb];
    bC[c] = *(const i64*)&sqC[bb][kb];
  }
  const float sb = sinvLs[bb], cbb = cbLs[bb];

  float bacc = 0.f;
#pragma unroll
  for (int tt = 0; tt < 2; ++tt) {        // 2 tiles per wave
    const int ridT = rid0 + w * 32 + tt * 16;
    int4v Ga = {0, 0, 0, 0}, Gb = {0, 0, 0, 0}, Gc = {0, 0, 0, 0};
#pragma unroll
    for (int c = 0; c < 4; ++c) {
      const i64 ahc = tt == 0 ? ah0[c] : ah1[c];
      const i64 alc = tt == 0 ? al0[c] : al1[c];
      Ga = __builtin_amdgcn_mfma_i32_16x16x32_i8(ahc, bA[c], Ga, 0, 0, 0);
      Gb = __builtin_amdgcn_mfma_i32_16x16x32_i8(ahc, bB[c], Gb, 0, 0, 0);
      Gb = __builtin_amdgcn_mfma_i32_16x16x32_i8(alc, bA[c], Gb, 0, 0, 0);
      Gc = __builtin_amdgcn_mfma_i32_16x16x32_i8(ahc, bC[c], Gc, 0, 0, 0);
      Gc = __builtin_amdgcn_mfma_i32_16x16x32_i8(alc, bB[c], Gc, 0, 0, 0);
    }
    // epilogue: C/D row = kg*4 + reg, col = bb (verified layout)
    const int rbase = ridT + kg * 4;
    const float4 cr = *(const float4*)(crow + rbase);
    const float4 ri = *(const float4*)(rowinv + rbase);
    const ushort4 adq = tt == 0 ? adq0 : adq1;
    const float crA[4] = {cr.x, cr.y, cr.z, cr.w};
    const float riA[4] = {ri.x, ri.y, ri.z, ri.w};
    const float adA[4] = {(float)adq.x, (float)adq.y, (float)adq.z, (float)adq.w};
    float ts = 0.f;
#pragma unroll
    for (int r = 0; r < 4; ++r) {
      const float dq = 16777216.f * (float)Ga[r] + 65536.f * (float)Gb[r] +
                       256.f * (float)Gc[r] + crA[r] + cbb;
      ts += adA[r] * fast_sin(dq * (riA[r] * sb));
    }
    ts += __shfl_xor(ts, 16, 64);
    ts += __shfl_xor(ts, 32, 64);
    bacc += ts;
  }
  if (lane < 16) part[w * 16 + lane] = bacc * (1.0f / 65535.f);
  __syncthreads();
  if (t < 16) {
    float ssum = part[t] + part[16 + t] + part[32 + t] + part[48 + t];
    aggp[quarter * 8192 + t * 512 + l] = ssum;   // aggp[quarter][b][l]
  }
}

// Zero quarters 2-3 of aggp (fp32 fallback path writes only halves 0-1).
__global__ __launch_bounds__(256) void kZeroTail(float* __restrict__ aggp) {
  aggp[16384 + blockIdx.x * 256 + threadIdx.x] = 0.f;
}

// Kernel B fallback (fp32 k2, R4 body) — only if ws_size can't hold planes.
__global__ __launch_bounds__(256) void kBf32(
    const float* __restrict__ k2, const float* __restrict__ adj,
    const float* __restrict__ s2T, float* __restrict__ aggp) {
  __shared__ float lk[256 * 36];
  __shared__ float part[64];
  const int t = threadIdx.x;
  const int rid0 = blockIdx.x * 256;
  const int rid = rid0 + t;
  const int l = rid0 >> 9;
  const int half = blockIdx.x & 1;

  float dot[16];
#pragma unroll
  for (int b = 0; b < 16; ++b) dot[b] = 0.f;

  for (int c = 0; c < 4; ++c) {
    __syncthreads();
#pragma unroll
    for (int k = 0; k < 8; ++k) {
      const int f = k * 256 + t, row = f >> 3, e = f & 7;
      const float4 v = *(const float4*)(k2 + (size_t)(rid0 + row) * 128 + c * 32 + e * 4);
      *(float4*)(lk + row * 36 + e * 4) = v;
    }
    __syncthreads();
    const float* myrow = lk + t * 36;
#pragma unroll
    for (int q = 0; q < 8; ++q) {
      const float4 kv = *(const float4*)(myrow + q * 4);
      f32x16 sa, sb, sc, sd;
      sload4(s2T + (c * 32 + q * 4) * 16, sa, sb, sc, sd);
#pragma unroll
      for (int b = 0; b < 16; ++b) dot[b] = fmaf(sa[b], kv.x, dot[b]);
#pragma unroll
      for (int b = 0; b < 16; ++b) dot[b] = fmaf(sb[b], kv.y, dot[b]);
#pragma unroll
      for (int b = 0; b < 16; ++b) dot[b] = fmaf(sc[b], kv.z, dot[b]);
#pragma unroll
      for (int b = 0; b < 16; ++b) dot[b] = fmaf(sd[b], kv.w, dot[b]);
    }
  }

#pragma unroll
  for (int b = 0; b < 16; ++b) {
    float v = adj[(size_t)b * 262144 + rid] * fast_sin(dot[b]);
#pragma unroll
    for (int off = 32; off > 0; off >>= 1) v += __shfl_down(v, off, 64);
    if ((t & 63) == 0) part[(t >> 6) * 16 + b] = v;
  }
  __syncthreads();
  if (t < 16) {
    float ssum = part[t] + part[16 + t] + part[32 + t] + part[48 + t];
    aggp[half * 8192 + t * 512 + l] = ssum;
  }
}

extern "C" void kernel_launch(void* const* d_in, const int* in_sizes, int n_in,
                              void* d_out, int out_size, void* d_ws, size_t ws_size,
                              hipStream_t stream) {
  const float* y0   = (const float*)d_in[0];  // [16,512]
  const float* bias = (const float*)d_in[1];  // [16,512,1]
  const float* adj  = (const float*)d_in[2];  // [16,512,512]
  const float* k0   = (const float*)d_in[3];  // [128,512,512]
  const float* k1   = (const float*)d_in[4];  // [128,512,128]
  const float* k2   = (const float*)d_in[5];  // [512,512,128]
  float* out = (float*)d_out;                 // [8,16,512] f32

  float* w      = (float*)d_ws;
  float* K0p    = w;                 // 131072 floats
  float* K1s    = w + 131072;        // 16384
  float* M      = w + 147456;        // 65536
  float* s2T    = w + 212992;        // 2048
  float* ybuf   = w + 215040;        // 16384
  float* racc   = w + 231424;        // 8192
  float* aggp   = w + 239616;        // 32768 (4 quarters x [16][512])
  float* rowinv = w + 272384;        // 262144
  float* crow   = w + 534528;        // 262144
  i64x2* kF2    = (i64x2*)(w + 796672);             // 64 MB i8 planes
  u16*   adjq   = (u16*)((char*)kF2 + 67108864);    // 8.5 MB u16 adj
  const bool useI8 =
      ws_size >= (size_t)796672 * 4 + (size_t)67108864 + (size_t)8388608;

  kPrep1<<<512, 256, 0, stream>>>(k0, K0p);
  kPrep2<<<64, 256, 0, stream>>>(k1, K1s);
  kPrep3<<<256, 256, 0, stream>>>(K0p, K1s, M);
  if (useI8) {
    kConvRow<<<16384, 256, 0, stream>>>(k2, kF2, rowinv, crow);
    kConvAdj<<<2048, 256, 0, stream>>>(adj, adjq);
  } else {
    kZeroTail<<<64, 256, 0, stream>>>(aggp);   // fallback writes halves only
  }

  kA2<<<256, 256, 0, stream>>>(y0, bias, M, aggp, ybuf, racc, s2T, out, 0, -1);

  for (int step = 0; step < 8; ++step) {
    for (int stage = 1; stage <= 4; ++stage) {
      if (useI8)
        kBi8<<<2048, 256, 0, stream>>>(kF2, adjq, s2T, rowinv, crow, aggp);
      else
        kBf32<<<1024, 256, 0, stream>>>(k2, adj, s2T, aggp);
      kA2<<<256, 256, 0, stream>>>(y0, bias, M, aggp, ybuf, racc, s2T, out, stage, step);
    }
  }
}